// Round 11
// baseline (550.259 us; speedup 1.0000x reference)
//
#include <hip/hip_runtime.h>
#include <hip/hip_bf16.h>
#include <math.h>

#define BB 4
#define NN 1024
#define DD 1024
#define HH 8
#define DH 64
#define NSR 1023

#define NS_Ac 3.4445f
#define NS_Bc (-4.775f)
#define NS_Cc 2.0315f

typedef short bf16x8 __attribute__((ext_vector_type(8)));
typedef float f32x4 __attribute__((ext_vector_type(4)));
#define MFMA16(a,b,c) __builtin_amdgcn_mfma_f32_16x16x32_bf16(a,b,c,0,0,0)

#define QS 72   // LDS row stride (bf16) for [rows][64] tiles
#define TS 40   // LDS row stride (bf16) for [rows][32] tiles
#define GS 40   // GEMM LDS row stride (bf16) for [64][32] tiles

static __device__ __forceinline__ float ldin(const void* p, size_t i, int f) {
  return f ? ((const float*)p)[i] : __bfloat162float(((const __hip_bfloat16*)p)[i]);
}
static __device__ __forceinline__ void stout(void* p, size_t i, float v, int f) {
  if (f) ((float*)p)[i] = v;
  else   ((__hip_bfloat16*)p)[i] = __float2bfloat16(v);
}
static __device__ __forceinline__ short f2bs(float x) {
  union { float f; unsigned u; } a; a.f = x;
  unsigned r = a.u + 0x7fffu + ((a.u >> 16) & 1u);
  return (short)(r >> 16);
}
static __device__ __forceinline__ float bs2f(short s) {
  union { unsigned u; float f; } a; a.u = ((unsigned)(unsigned short)s) << 16;
  return a.f;
}
static __device__ __forceinline__ f32x4 fz4() { f32x4 z = {0.f,0.f,0.f,0.f}; return z; }
static __device__ __forceinline__ bf16x8 bz8() { bf16x8 z = {0,0,0,0,0,0,0,0}; return z; }

// 64x64 split-bf16 matmul: C += A * B^T (A,B row-major [64][QS] hi/lo pairs in LDS)
static __device__ __forceinline__ void mm64(const short* __restrict__ Ah, const short* __restrict__ Al,
                                            const short* __restrict__ Bh, const short* __restrict__ Bl,
                                            f32x4* acc, int w, int l15, int quad) {
#pragma unroll
  for (int kc = 0; kc < 64; kc += 32) {
    bf16x8 ah = *(const bf16x8*)&Ah[(w*16 + l15)*QS + kc + quad*8];
    bf16x8 al = *(const bf16x8*)&Al[(w*16 + l15)*QS + kc + quad*8];
#pragma unroll
    for (int es = 0; es < 4; es++) {
      bf16x8 bh = *(const bf16x8*)&Bh[(es*16 + l15)*QS + kc + quad*8];
      bf16x8 bl = *(const bf16x8*)&Bl[(es*16 + l15)*QS + kc + quad*8];
      acc[es] = MFMA16(ah, bh, acc[es]);
      acc[es] = MFMA16(ah, bl, acc[es]);
      acc[es] = MFMA16(al, bh, acc[es]);
    }
  }
}
// write fragment (fp32) as hi/lo bf16 pair at output coords
static __device__ __forceinline__ void st_hl(short* __restrict__ Dh, short* __restrict__ Dl,
                                             const f32x4* v, int w, int l15, int quad) {
#pragma unroll
  for (int es = 0; es < 4; es++)
#pragma unroll
    for (int rr = 0; rr < 4; rr++) {
      int row = w*16 + quad*4 + rr, col = es*16 + l15;
      float x = v[es][rr];
      short h = f2bs(x);
      Dh[row*QS + col] = h;
      Dl[row*QS + col] = f2bs(x - bs2f(h));
    }
}

// ---------------- fused prep: weight converters + small tensors + flag + RMSNorm/gates ----------------
// blocks: [0,384) BqkvT; [384,640) wtT; [640,768) woT2; [768,812) small+flag; [812,1324) wo_bf;
//         [1324,1324+4096): rmsnorm+gates rows (reads raw inputs, flag computed locally)
__global__ __launch_bounds__(256) void k_prep(
    const void* wq, const void* wk, const void* wv,
    const void* w_target, const void* wo, const void* w_lr, const void* w_gates, const void* rms_w,
    short* __restrict__ BqkvT, short* __restrict__ wtT, short* __restrict__ woT2,
    short* __restrict__ wo_bf, float* __restrict__ lrw, float* __restrict__ gw,
    float* __restrict__ rms_f, int* __restrict__ flag,
    const void* tokens, float* __restrict__ t, short* __restrict__ t_bf,
    float* __restrict__ gates, float* __restrict__ lr, float* __restrict__ mlr)
{
  const int f = (((const unsigned short*)rms_w)[0] == 0x3F80) ? 0 : 1;
  int bx = blockIdx.x; int tid = threadIdx.x;
  if (bx >= 1324) {
    // ---- rmsnorm + gates + lr/mlr ----
    int row = bx - 1324;
    int b = row >> 10, n = row & 1023;
    __shared__ float red[256];
    __shared__ float red2[4][10];
    float xv[4]; float acc = 0.f;
#pragma unroll
    for (int i = 0; i < 4; i++) {
      xv[i] = ldin(tokens, (size_t)row*DD + tid + 256*i, f);
      acc += xv[i]*xv[i];
    }
    red[tid] = acc; __syncthreads();
    for (int s = 128; s > 0; s >>= 1) { if (tid < s) red[tid] += red[tid+s]; __syncthreads(); }
    float r = rsqrtf(red[0] / DD + 1.1920929e-07f);
    float a10[10] = {0,0,0,0,0,0,0,0,0,0};
#pragma unroll
    for (int i = 0; i < 4; i++) {
      int d = tid + 256*i;
      float v = xv[i] * r * ldin(rms_w, d, f);
      t[(size_t)row*DD + d] = v;
      t_bf[(size_t)row*DD + d] = f2bs(v);
#pragma unroll
      for (int h = 0; h < HH; h++) a10[h] += v * ldin(w_gates, (size_t)d*HH + h, f);
      a10[8] += v * ldin(w_lr, (size_t)d*2, f);
      a10[9] += v * ldin(w_lr, (size_t)d*2 + 1, f);
    }
    int lane = tid & 63, w = tid >> 6;
#pragma unroll
    for (int c = 0; c < 10; c++) {
      float a = a10[c];
      for (int s = 32; s > 0; s >>= 1) a += __shfl_xor(a, s, 64);
      if (lane == 0) red2[w][c] = a;
    }
    __syncthreads();
    if (tid < 10) {
      int c = tid;
      float sum = red2[0][c]+red2[1][c]+red2[2][c]+red2[3][c];
      float sg = 1.f / (1.f + __expf(-sum));
      if (c < 8)      gates[((size_t)b*HH + c)*NN + n] = sg;
      else if (c == 8) lr[row]  = sg * 0.01f;
      else             mlr[row] = sg * 0.01f;
    }
    return;
  }
  if (bx >= 768) {
    if (bx < 812) {
      if (bx == 768 && tid == 0) *flag = f;
      int idx = (bx - 768)*256 + tid;
      if (idx < 2048) lrw[idx] = ldin(w_lr, idx, f);
      else if (idx < 10240) gw[idx-2048] = ldin(w_gates, idx-2048, f);
      else if (idx < 11264) rms_f[idx-10240] = ldin(rms_w, idx-10240, f);
    } else {
      size_t base = (size_t)(bx - 812)*1024;
#pragma unroll
      for (int j = 0; j < 4; j++) {
        size_t i2 = base + tid + 256*j;
        wo_bf[i2] = f2bs(ldin(wo, i2, f));
      }
    }
    return;
  }
  const void* src; short* dst; int sld, dld, srow0, scol0, drow0; size_t soff = 0;
  if (bx < 384) {
    int x = bx & 15, y = bx >> 4;
    int n0 = y*64; int which = n0 >> 9, h = (n0 >> 6) & 7;
    src = (which==0) ? wq : (which==1) ? wk : wv;
    soff = (size_t)h*65536;
    sld = 64; dld = 1024; srow0 = x*64; scol0 = 0; drow0 = n0; dst = BqkvT;
  } else if (bx < 640) {
    int r = bx - 384; int x = r & 15, y = r >> 4;
    src = w_target; dst = wtT; sld = 1024; dld = 1024;
    srow0 = x*64; scol0 = y*64; drow0 = scol0;
  } else {
    int r = bx - 640; int x = r & 7, y = r >> 3;
    src = wo; dst = woT2; sld = 1024; dld = 512;
    srow0 = x*64; scol0 = y*64; drow0 = scol0;
  }
  __shared__ float T[64][65];
  int r4 = tid >> 4, c4 = (tid & 15)*4;
  for (int rr = r4; rr < 64; rr += 16)
#pragma unroll
    for (int j = 0; j < 4; j++)
      T[rr][c4+j] = ldin(src, soff + (size_t)(srow0+rr)*sld + scol0 + c4 + j, f);
  __syncthreads();
  int dc = tid >> 2, seg = tid & 3;
  bf16x8 o1, o2;
#pragma unroll
  for (int j = 0; j < 8; j++) { o1[j] = f2bs(T[seg*16+j][dc]); o2[j] = f2bs(T[seg*16+8+j][dc]); }
  *(bf16x8*)&dst[(size_t)(drow0+dc)*dld + srow0 + seg*16]     = o1;
  *(bf16x8*)&dst[(size_t)(drow0+dc)*dld + srow0 + seg*16 + 8] = o2;
}

// fp32 [R][C] -> bf16 [C][R] (kept for the t->tT transpose)
__global__ __launch_bounds__(256) void k_transp(
    const float* __restrict__ src, size_t sStepZ, int sld,
    short* __restrict__ dst, size_t dStepZ, int dld,
    const float* __restrict__ coef, int zIsBh, int nz)
{
  int z = blockIdx.z;
  const float* sb = src + (size_t)z*sStepZ;
  short* db = dst + (size_t)z*dStepZ;
  const float* cb = coef ? coef + (size_t)(zIsBh ? (z>>3) : z)*1024 : (const float*)0;
  int x0 = blockIdx.x*64, y0 = blockIdx.y*64;
  __shared__ float T[64][65];
  int tid = threadIdx.x;
  int r4 = tid >> 4, c4 = (tid & 15)*4;
  for (int rr = r4; rr < 64; rr += 16) {
    int rg = x0 + rr;
    bool val = rg < nz;
    float cf = val ? (cb ? cb[rg] : 1.f) : 0.f;
    float4 v = val ? *(const float4*)&sb[(size_t)rg*sld + y0 + c4] : make_float4(0,0,0,0);
    T[rr][c4+0] = v.x*cf; T[rr][c4+1] = v.y*cf; T[rr][c4+2] = v.z*cf; T[rr][c4+3] = v.w*cf;
  }
  __syncthreads();
  int dc = tid >> 2, seg = tid & 3;
  bf16x8 o1, o2;
#pragma unroll
  for (int j = 0; j < 8; j++) { o1[j] = f2bs(T[seg*16+j][dc]); o2[j] = f2bs(T[seg*16+8+j][dc]); }
  *(bf16x8*)&db[(size_t)(y0+dc)*dld + x0 + seg*16]     = o1;
  *(bf16x8*)&db[(size_t)(y0+dc)*dld + x0 + seg*16 + 8] = o2;
}

// ---------------- 5-way fused fp32->bf16T transposes (post-bwd) ----------------
__global__ __launch_bounds__(256) void k_transp5(
    const float* __restrict__ dq, const float* __restrict__ dk, const float* __restrict__ dv,
    const float* __restrict__ predf, const float* __restrict__ o,
    short* __restrict__ dqT, short* __restrict__ dkT, short* __restrict__ dvT,
    short* __restrict__ errT, short* __restrict__ oT,
    const float* __restrict__ lr, const float* __restrict__ mlr)
{
  int bx = blockIdx.x;
  const float* src; short* dst; const float* cb; int sld, dld, x0, y0;
  size_t sStep, dStep; int z;
  if (bx < 1536) {
    int which = bx >> 9; int r = bx & 511;
    z = r >> 4; x0 = (r & 15)*64; y0 = 0;
    sld = 64; dld = 1024; sStep = 65536; dStep = 65536;
    if (which == 0)      { src = dq; dst = dqT; cb = lr; }
    else if (which == 1) { src = dk; dst = dkT; cb = lr; }
    else                 { src = dv; dst = dvT; cb = mlr; }
    cb += (size_t)(z >> 3)*1024;
  } else if (bx < 2560) {
    int r = bx - 1536; z = r >> 8; x0 = (r & 15)*64; y0 = ((r >> 4) & 15)*64;
    src = predf; dst = errT; cb = (const float*)0;
    sld = 1024; dld = 1024; sStep = 1048576; dStep = 1048576;
  } else {
    int r = bx - 2560; z = r >> 7; x0 = (r & 15)*64; y0 = ((r >> 4) & 7)*64;
    src = o; dst = oT; cb = mlr + (size_t)z*1024;
    sld = 512; dld = 1024; sStep = 524288; dStep = 524288;
  }
  src += (size_t)z*sStep; dst += (size_t)z*dStep;
  __shared__ float T[64][65];
  int tid = threadIdx.x;
  int r4 = tid >> 4, c4 = (tid & 15)*4;
  for (int rr = r4; rr < 64; rr += 16) {
    int rg = x0 + rr;
    bool val = rg < 1023;
    float cf = val ? (cb ? cb[rg] : 1.f) : 0.f;
    float4 v = val ? *(const float4*)&src[(size_t)rg*sld + y0 + c4] : make_float4(0,0,0,0);
    T[rr][c4+0] = v.x*cf; T[rr][c4+1] = v.y*cf; T[rr][c4+2] = v.z*cf; T[rr][c4+3] = v.w*cf;
  }
  __syncthreads();
  int dc = tid >> 2, seg = tid & 3;
  bf16x8 o1, o2;
#pragma unroll
  for (int j = 0; j < 8; j++) { o1[j] = f2bs(T[seg*16+j][dc]); o2[j] = f2bs(T[seg*16+8+j][dc]); }
  *(bf16x8*)&dst[(size_t)(y0+dc)*dld + x0 + seg*16]     = o1;
  *(bf16x8*)&dst[(size_t)(y0+dc)*dld + x0 + seg*16 + 8] = o2;
}

// ---------------- 128x128 MFMA GEMM (big shapes): C[M x N] = A[M][K] * B^T ----------------
// Dual-mode: blocks with blockIdx.y >= ysplit use the second parameter set (fused launches).
// eps: 0 (qkv + vbT transpose write), 1 (predf + d_out), 2 (tvbuf), 3 (du_bf gated)
__global__ __launch_bounds__(256) void k_gemm2(
    const short* __restrict__ A, const short* __restrict__ B,
    int lda, int ldb, int K, int M, int rowmode, int ep,
    float* __restrict__ O0, short* __restrict__ OS, void* __restrict__ OD,
    short* __restrict__ VT, const float* __restrict__ gates, const int* __restrict__ flag,
    int ysplit, const short* __restrict__ A2, const short* __restrict__ B2,
    int lda2, int ldb2, int K2, int M2, int rowmode2, int ep2p,
    float* __restrict__ O02, void* __restrict__ OD2)
{
  int yb = blockIdx.y;
  const short* Au = A; const short* Bu = B;
  int ldav = lda, ldbv = ldb, Kv = K, Mv = M, rmv = rowmode, epv = ep;
  float* O0v = O0; void* ODv = OD;
  if (ysplit && yb >= ysplit) {
    yb -= ysplit; Au = A2; Bu = B2; ldav = lda2; ldbv = ldb2; Kv = K2; Mv = M2;
    rmv = rowmode2; epv = ep2p; O0v = O02; ODv = OD2;
  }
  int m0 = blockIdx.x*128, n0 = yb*128;
  __shared__ __align__(16) short sm2[17408];
  short* As = sm2;          // 128*GS = 5120
  short* Bs = sm2 + 5120;   // 5120
  int tid = threadIdx.x;
  int lane = tid & 63, w = tid >> 6;
  int wr = w >> 1, wc = w & 1;
  int l15 = lane & 15, quad = lane >> 4;
  int row = tid >> 1, col16 = (tid & 1)*16;
  int r = m0 + row;
  int arow;
  if (rmv == 1)      { int b = r / 1023; arow = r + b + 1; }
  else if (rmv == 2) { int b = r / 1023; arow = r + b; }
  else arow = r;
  bool aval = (r < Mv);
  const short* Ap = Au + (size_t)arow*ldav + col16;
  const short* Bp = Bu + (size_t)(n0+row)*ldbv + col16;
  f32x4 acc[4][4];
#pragma unroll
  for (int mi = 0; mi < 4; mi++)
#pragma unroll
    for (int ni = 0; ni < 4; ni++) acc[mi][ni] = fz4();
  bf16x8 av0 = aval ? *(const bf16x8*)(Ap) : bz8();
  bf16x8 av1 = aval ? *(const bf16x8*)(Ap + 8) : bz8();
  bf16x8 bv0 = *(const bf16x8*)(Bp);
  bf16x8 bv1 = *(const bf16x8*)(Bp + 8);
  for (int kb = 0; kb < Kv; kb += 32) {
    __syncthreads();
    *(bf16x8*)&As[row*GS + col16]     = av0;
    *(bf16x8*)&As[row*GS + col16 + 8] = av1;
    *(bf16x8*)&Bs[row*GS + col16]     = bv0;
    *(bf16x8*)&Bs[row*GS + col16 + 8] = bv1;
    __syncthreads();
    if (kb + 32 < Kv) {
      av0 = aval ? *(const bf16x8*)(Ap + kb + 32) : bz8();
      av1 = aval ? *(const bf16x8*)(Ap + kb + 40) : bz8();
      bv0 = *(const bf16x8*)(Bp + kb + 32);
      bv1 = *(const bf16x8*)(Bp + kb + 40);
    }
    bf16x8 afr[4], bfr[4];
#pragma unroll
    for (int mi = 0; mi < 4; mi++)
      afr[mi] = *(const bf16x8*)&As[(wr*64 + mi*16 + l15)*GS + quad*8];
#pragma unroll
    for (int ni = 0; ni < 4; ni++)
      bfr[ni] = *(const bf16x8*)&Bs[(wc*64 + ni*16 + l15)*GS + quad*8];
#pragma unroll
    for (int mi = 0; mi < 4; mi++)
#pragma unroll
      for (int ni = 0; ni < 4; ni++)
        acc[mi][ni] = MFMA16(afr[mi], bfr[ni], acc[mi][ni]);
  }
  const int f = flag ? *flag : 1;
#pragma unroll
  for (int mi = 0; mi < 4; mi++)
#pragma unroll
    for (int ni = 0; ni < 4; ni++)
#pragma unroll
      for (int rix = 0; rix < 4; rix++) {
        int rr = m0 + wr*64 + mi*16 + quad*4 + rix;
        if (rr >= Mv) continue;
        int c = n0 + wc*64 + ni*16 + l15;
        float val = acc[mi][ni][rix];
        if (epv == 0) {
          int which = c >> 9; int h = (c >> 6) & 7; int e = c & 63;
          int b = rr >> 10; int n = rr & 1023;
          OS[(size_t)which*2097152 + (((size_t)b*8 + h)*1024 + n)*64 + e] = f2bs(val);
        } else if (epv == 1) {
          O0v[(size_t)rr*1024 + c] = val;
          stout(ODv, (size_t)rr*1024 + c, val, f);
        } else if (epv == 2) {
          O0v[(size_t)rr*1024 + c] = val;
        } else {
          int b = rr / 1023; int n = rr % 1023;
          int h = c >> 6;
          float g = gates[((size_t)b*8 + h)*1024 + n];
          OS[((size_t)b*1024 + n)*512 + c] = f2bs(val * g);
        }
      }
  // ep0: v-tiles (c in [1024,1536)) additionally write transposed vbT via LDS stage
  if (epv == 0 && n0 >= 1024) {
    short* ST = sm2;   // [128 c][136: m 0..63 at 0, m 64..127 at 72]
    __syncthreads();
#pragma unroll
    for (int mi = 0; mi < 4; mi++)
#pragma unroll
      for (int ni = 0; ni < 4; ni++)
#pragma unroll
        for (int rix = 0; rix < 4; rix++) {
          int ml = wr*64 + mi*16 + quad*4 + rix;
          int cl = wc*64 + ni*16 + l15;
          int mo = ml + ((ml >> 6) << 3);   // +8 if ml>=64
          ST[cl*136 + mo] = f2bs(acc[mi][ni][rix]);
        }
    __syncthreads();
    int r2 = tid >> 1;
    int sg = tid & 1;
    int cg = n0 + r2;
    int h = (cg >> 6) & 7;
    int e = cg & 63;
    int b = m0 >> 10;
    int bh = b*8 + h;
    size_t dst = ((size_t)bh*64 + e)*1024 + (m0 & 1023) + sg*64;
    int so = r2*136 + sg*72;
#pragma unroll
    for (int j = 0; j < 64; j += 8)
      *(bf16x8*)&VT[dst + j] = *(const bf16x8*)&ST[so + j];
  }
}

// ---------------- universal MFMA GEMM (64x64, K-step 64): kept for ep4/ep5 fused shapes ----------------
__global__ __launch_bounds__(256) void k_gemm_bf(
    const short* __restrict__ A, const short* __restrict__ B,
    int lda, int ldb, int K, int M, int rowmode, int ep,
    size_t aStepBh, size_t aStepB, size_t bStepBh, size_t bStepB,
    float* __restrict__ O0, short* __restrict__ OS, void* __restrict__ OD,
    size_t out_off, const float* __restrict__ gates, const int* __restrict__ flag,
    const short* __restrict__ A2, const short* __restrict__ B2,
    size_t bStepB2, size_t out_off2, int ldb2)
{
  int z = blockIdx.z;
  const short* Au = A; const short* Bu = B;
  size_t bStepBv = bStepB; size_t out_offv = out_off;
  int epv = ep; int ldbv = ldb;
  if (ep == 4 && z >= 32) { Bu = B2; out_offv = out_off2; z -= 32; }
  if (ep == 5 && z >= 32) { Au = A2; Bu = B2; bStepBv = bStepB2; ldbv = ldb2; epv = 6; z -= 32; }
  int zb = z >> 3;
  const short* Ab = Au + (size_t)z*aStepBh + (size_t)zb*aStepB;
  const short* Bb = Bu + (size_t)z*bStepBh + (size_t)zb*bStepBv;
  int m0 = blockIdx.x*64, n0 = blockIdx.y*64;
  __shared__ __align__(16) short AsBs[9216];
  short* As = AsBs;
  short* Bs = AsBs + 4608;
  int tid = threadIdx.x;
  int lane = tid & 63, w = tid >> 6;
  int l15 = lane & 15, quad = lane >> 4;
  int row = tid >> 2, col16 = (tid & 3)*16;
  int r = m0 + row;
  int arow;
  if (rowmode == 1)      { int b = r / 1023; arow = r + b + 1; }
  else if (rowmode == 2) { int b = r / 1023; arow = r + b; }
  else arow = r;
  bool aval = (r < M);
  const short* Ap = Ab + (size_t)arow*lda + col16;
  const short* Bp = Bb + (size_t)(n0+row)*ldbv + col16;
  f32x4 acc[4] = {fz4(),fz4(),fz4(),fz4()};
  bf16x8 av0 = aval ? *(const bf16x8*)(Ap) : bz8();
  bf16x8 av1 = aval ? *(const bf16x8*)(Ap + 8) : bz8();
  bf16x8 bv0 = *(const bf16x8*)(Bp);
  bf16x8 bv1 = *(const bf16x8*)(Bp + 8);
  for (int kb = 0; kb < K; kb += 64) {
    __syncthreads();
    *(bf16x8*)&As[row*QS + col16]     = av0;
    *(bf16x8*)&As[row*QS + col16 + 8] = av1;
    *(bf16x8*)&Bs[row*QS + col16]     = bv0;
    *(bf16x8*)&Bs[row*QS + col16 + 8] = bv1;
    __syncthreads();
    if (kb + 64 < K) {
      av0 = aval ? *(const bf16x8*)(Ap + kb + 64) : bz8();
      av1 = aval ? *(const bf16x8*)(Ap + kb + 72) : bz8();
      bv0 = *(const bf16x8*)(Bp + kb + 64);
      bv1 = *(const bf16x8*)(Bp + kb + 72);
    }
#pragma unroll
    for (int kc = 0; kc < 64; kc += 32) {
      bf16x8 afr = *(const bf16x8*)&As[(w*16 + l15)*QS + kc + quad*8];
#pragma unroll
      for (int es = 0; es < 4; es++) {
        bf16x8 bfr = *(const bf16x8*)&Bs[(es*16 + l15)*QS + kc + quad*8];
        acc[es] = MFMA16(afr, bfr, acc[es]);
      }
    }
  }
  const int f = flag ? *flag : 1;
#pragma unroll
  for (int es = 0; es < 4; es++) {
#pragma unroll
    for (int rix = 0; rix < 4; rix++) {
      int rr = m0 + w*16 + quad*4 + rix;
      if (rr >= M) continue;
      int c = n0 + es*16 + l15;
      float val = acc[es][rix];
      if (epv == 4) {
        stout(OD, out_offv + ((size_t)z*1024 + rr)*64 + c, val, f);
      } else if (epv == 5) {
        O0[((size_t)z*64 + rr)*1024 + c] = val;
      } else if (epv == 6) {
        O0[((size_t)(32 + z)*64 + rr)*1024 + c] = val;
      }
    }
  }
}

// ---------------- attention forward: flash, MFMA bf16, software-pipelined ----------------
__global__ __launch_bounds__(256) void k_attn_fwd(
    const short* __restrict__ qb, const short* __restrict__ kb, const short* __restrict__ vbT,
    const float* __restrict__ gates,
    float* __restrict__ o, short* __restrict__ o_bf,
    float* __restrict__ mrow, float* __restrict__ lrow)
{
  int pp = blockIdx.x >> 8;
  int xx = (blockIdx.x >> 5) & 7;
  int bh = blockIdx.x & 31;
  int it = pp ? xx : (15 - xx);
  int i0 = it*64;
  int b = bh >> 3, h = bh & 7;
  __shared__ __align__(16) short Qs[64*QS];
  __shared__ __align__(16) short Ks[32*QS];
  __shared__ __align__(16) short VsT[64*TS];
  __shared__ __align__(16) short Ps[64*TS];
  int tid = threadIdx.x;
  int lane = tid & 63, w = tid >> 6;
  int l15 = lane & 15, quad = lane >> 4;
  int sr = tid >> 3, sc = (tid & 7) * 8;
  int sr2 = tid >> 2, sc2 = (tid & 3) * 8;
  int rsw = (l15 >> 2) & 3;
  for (int rr = sr; rr < 64; rr += 32)
    *(bf16x8*)&Qs[rr*QS + sc] = *(const bf16x8*)&qb[((size_t)bh*1024 + i0 + rr)*64 + sc];
  f32x4 oa[4] = {fz4(),fz4(),fz4(),fz4()};
  float m_st[4] = {-1e30f,-1e30f,-1e30f,-1e30f};
  float l_st[4] = {0.f,0.f,0.f,0.f};
  int jiters = 2*it + 2;
  bf16x8 rk = *(const bf16x8*)&kb[((size_t)bh*1024 + sr)*64 + sc];
  bf16x8 rv = *(const bf16x8*)&vbT[((size_t)bh*64 + sr2)*1024 + sc2];
  for (int jc = 0; jc < jiters; jc++) {
    int j0 = jc*32;
    __syncthreads();
    *(bf16x8*)&Ks[sr*QS + sc]    = rk;
    *(bf16x8*)&VsT[sr2*TS + sc2] = rv;
    __syncthreads();
    if (jc + 1 < jiters) {
      int j1 = j0 + 32;
      rk = *(const bf16x8*)&kb[((size_t)bh*1024 + j1 + sr)*64 + sc];
      rv = *(const bf16x8*)&vbT[((size_t)bh*64 + sr2)*1024 + j1 + sc2];
    }
    f32x4 sa[2] = {fz4(),fz4()};
#pragma unroll
    for (int kc = 0; kc < 64; kc += 32) {
      bf16x8 afr = *(const bf16x8*)&Qs[(w*16 + l15)*QS + kc + quad*8];
#pragma unroll
      for (int ni = 0; ni < 2; ni++) {
        bf16x8 bfr = *(const bf16x8*)&Ks[(ni*16 + l15)*QS + kc + quad*8];
        sa[ni] = MFMA16(afr, bfr, sa[ni]);
      }
    }
#pragma unroll
    for (int r = 0; r < 4; r++) {
      int gi = i0 + w*16 + quad*4 + r;
      float s0 = sa[0][r]*0.125f, s1 = sa[1][r]*0.125f;
      if (j0 + l15 > gi)      s0 = -1e30f;
      if (j0 + 16 + l15 > gi) s1 = -1e30f;
      float rm = fmaxf(s0, s1);
      rm = fmaxf(rm, __shfl_xor(rm, 1, 64));
      rm = fmaxf(rm, __shfl_xor(rm, 2, 64));
      rm = fmaxf(rm, __shfl_xor(rm, 4, 64));
      rm = fmaxf(rm, __shfl_xor(rm, 8, 64));
      float m_new = fmaxf(m_st[r], rm);
      float alpha = __expf(m_st[r] - m_new);
      float p0 = __expf(s0 - m_new), p1 = __expf(s1 - m_new);
      float rs = p0 + p1;
      rs += __shfl_xor(rs, 1, 64);
      rs += __shfl_xor(rs, 2, 64);
      rs += __shfl_xor(rs, 4, 64);
      rs += __shfl_xor(rs, 8, 64);
      l_st[r] = l_st[r]*alpha + rs;
      m_st[r] = m_new;
#pragma unroll
      for (int es = 0; es < 4; es++) oa[es][r] *= alpha;
      int rowp = w*16 + quad*4 + r;
      int lo3 = l15 & 7, g0 = l15 >> 3;
      Ps[rowp*TS + ((( g0      ^ quad) << 3) | lo3)] = f2bs(p0);
      Ps[rowp*TS + ((((g0 | 2) ^ quad) << 3) | lo3)] = f2bs(p1);
    }
    bf16x8 pa = *(const bf16x8*)&Ps[(w*16 + l15)*TS + ((quad ^ rsw) << 3)];
#pragma unroll
    for (int es = 0; es < 4; es++) {
      bf16x8 bv = *(const bf16x8*)&VsT[(es*16 + l15)*TS + quad*8];
      oa[es] = MFMA16(pa, bv, oa[es]);
    }
  }
#pragma unroll
  for (int r = 0; r < 4; r++) {
    int gi = i0 + w*16 + quad*4 + r;
    float g = gates[(size_t)bh*1024 + gi] / l_st[r];
#pragma unroll
    for (int es = 0; es < 4; es++) {
      float val = oa[es][r] * g;
      size_t oi = ((size_t)b*1024 + gi)*512 + h*64 + es*16 + l15;
      o[oi] = val;
      o_bf[oi] = f2bs(val);
    }
    if (l15 == 0) {
      mrow[(size_t)bh*1024 + gi] = m_st[r];
      lrow[(size_t)bh*1024 + gi] = l_st[r];
    }
  }
}

// ---------------- layernorm(tv) - pred -> err fp32 (in predf) + err_bf ----------------
__global__ void k_lnsub(const float* __restrict__ tvbuf, float* __restrict__ predf,
                        short* __restrict__ err_bf) {
  int r = blockIdx.x; int b = r / 1023; int prow = r + b;
  const float* tvr = tvbuf + (size_t)r*1024;
  __shared__ float red[256];
  float s1 = 0.f, s2 = 0.f;
  float xv[4];
#pragma unroll
  for (int i = 0; i < 4; i++) {
    xv[i] = tvr[threadIdx.x + 256*i];
    s1 += xv[i]; s2 += xv[i]*xv[i];
  }
  red[threadIdx.x] = s1; __syncthreads();
  for (int s = 128; s > 0; s >>= 1){ if (threadIdx.x < s) red[threadIdx.x] += red[threadIdx.x+s]; __syncthreads(); }
  float mean = red[0] / 1024.f; __syncthreads();
  red[threadIdx.x] = s2; __syncthreads();
  for (int s = 128; s > 0; s >>= 1){ if (threadIdx.x < s) red[threadIdx.x] += red[threadIdx.x+s]; __syncthreads(); }
  float var = red[0]/1024.f - mean*mean;
  float rstd = rsqrtf(var + 1e-5f);
  float* er = predf + (size_t)prow*1024;
#pragma unroll
  for (int i = 0; i < 4; i++) {
    int d = threadIdx.x + 256*i;
    float e = (xv[i]-mean)*rstd - er[d];
    er[d] = e;
    err_bf[(size_t)prow*1024 + d] = f2bs(e);
  }
}

// ---------------- k/du/q transposes + delta (fused, 1-D grid) ----------------
__global__ __launch_bounds__(256) void k_t16(const short* __restrict__ qv, const short* __restrict__ du,
                                             short* __restrict__ kbT, short* __restrict__ duT,
                                             short* __restrict__ qbT,
                                             const float* __restrict__ o, const float* __restrict__ gates,
                                             float* __restrict__ delta) {
  int bx = blockIdx.x; int tid = threadIdx.x;
  if (bx >= 1536) {
    int r = bx - 1536; int b = r / 1023; int n = r % 1023;
    int w = tid >> 6, lane = tid & 63;
    size_t base = ((size_t)b*1024 + n)*512;
    float p1 = bs2f(du[base + tid])       * o[base + tid];
    float p2 = bs2f(du[base + tid + 256]) * o[base + tid + 256];
    for (int s = 32; s > 0; s >>= 1) { p1 += __shfl_xor(p1, s, 64); p2 += __shfl_xor(p2, s, 64); }
    if (lane == 0) {
      size_t i1 = ((size_t)b*8 + w)*1024 + n;
      size_t i2 = ((size_t)b*8 + w + 4)*1024 + n;
      delta[i1] = p1 / gates[i1];
      delta[i2] = p2 / gates[i2];
    }
    return;
  }
  int z = bx >> 4;
  int r0 = (bx & 15)*64;
  const short* sb; short* db; int sld, nvalid;
  if (z < 32) {
    sb = qv + (size_t)(32 + z)*65536; sld = 64; nvalid = 1024;
    db = kbT + (size_t)z*65536;
  } else if (z < 64) {
    int zz = z - 32;
    sb = du + (size_t)(zz >> 3)*524288 + (size_t)(zz & 7)*64;
    sld = 512; nvalid = 1023;
    db = duT + (size_t)zz*65536;
  } else {
    int zz = z - 64;
    sb = qv + (size_t)zz*65536; sld = 64; nvalid = 1024;
    db = qbT + (size_t)zz*65536;
  }
  __shared__ float T[64][65];
  int sr = tid >> 3, sc = (tid & 7)*8;
  for (int rr = sr; rr < 64; rr += 32) {
    int n = r0 + rr;
    bf16x8 v = (n < nvalid) ? *(const bf16x8*)&sb[(size_t)n*sld + sc] : bz8();
#pragma unroll
    for (int j = 0; j < 8; j++) T[rr][sc+j] = bs2f(v[j]);
  }
  __syncthreads();
  int dc = tid >> 2, seg = tid & 3;
  bf16x8 o1, o2;
#pragma unroll
  for (int j = 0; j < 8; j++) { o1[j] = f2bs(T[seg*16+j][dc]); o2[j] = f2bs(T[seg*16+8+j][dc]); }
  *(bf16x8*)&db[(size_t)dc*1024 + r0 + seg*16]     = o1;
  *(bf16x8*)&db[(size_t)dc*1024 + r0 + seg*16 + 8] = o2;
}

// ---------------- attention backward, merged dv/dk (blocks 0..511) + dq (512..1023) ----------------
__global__ __launch_bounds__(256) void k_bwd(
    const short* __restrict__ qb, const short* __restrict__ kb, const short* __restrict__ vb,
    const short* __restrict__ du_bf, const short* __restrict__ qbT, const short* __restrict__ duT,
    const short* __restrict__ kbT,
    const float* __restrict__ mrow, const float* __restrict__ lrow, const float* __restrict__ delta,
    float* __restrict__ dv, float* __restrict__ dk, float* __restrict__ dq)
{
  __shared__ __align__(16) short smem[24320];
  int tid = threadIdx.x;
  int lane = tid & 63, w = tid >> 6;
  int l15 = lane & 15, quad = lane >> 4;
  int sr = tid >> 3, sc = (tid & 7) * 8;
  int sr2 = tid >> 2, sc2 = (tid & 3) * 8;
  int rsw = (l15 >> 2) & 3;

  if (blockIdx.x < 512) {
    int pp = blockIdx.x >> 8;
    int xx = (blockIdx.x >> 5) & 7;
    int bh = blockIdx.x & 31;
    int jt = pp ? (15 - xx) : xx;
    int j0 = jt*64;
    int b = bh >> 3, h = bh & 7;
    short* Ks   = smem;
    short* Vs   = Ks + 4608;
    short* Qs   = Vs + 4608;
    short* DUs  = Qs + 2304;
    short* QsT  = DUs + 2304;
    short* DUsT = QsT + 2560;
    short* PsT  = DUsT + 2560;
    short* DsT  = PsT + 2560;
    float* mvs  = (float*)(DsT + 2560);
    float* lvs  = mvs + 32;
    float* dls  = lvs + 32;
    for (int rr = sr; rr < 64; rr += 32) {
      *(bf16x8*)&Ks[rr*QS + sc] = *(const bf16x8*)&kb[((size_t)bh*1024 + j0 + rr)*64 + sc];
      *(bf16x8*)&Vs[rr*QS + sc] = *(const bf16x8*)&vb[((size_t)bh*1024 + j0 + rr)*64 + sc];
    }
    f32x4 dva[4] = {fz4(),fz4(),fz4(),fz4()};
    f32x4 dka[4] = {fz4(),fz4(),fz4(),fz4()};
    int iters = 32 - 2*jt;
    int gi0 = j0 + sr;
    bf16x8 rq   = *(const bf16x8*)&qb[((size_t)bh*1024 + gi0)*64 + sc];
    bf16x8 rdu  = (gi0 < NSR) ? *(const bf16x8*)&du_bf[((size_t)b*1024 + gi0)*512 + h*64 + sc] : bz8();
    bf16x8 rqT  = *(const bf16x8*)&qbT[((size_t)bh*64 + sr2)*1024 + j0 + sc2];
    bf16x8 rduT = *(const bf16x8*)&duT[((size_t)bh*64 + sr2)*1024 + j0 + sc2];
    float rm = 0.f, rl = 1.f, rd = 0.f;
    if (tid < 32) {
      int gi2 = j0 + tid;
      rm = mrow[(size_t)bh*1024 + gi2];
      rl = lrow[(size_t)bh*1024 + gi2];
      rd = (gi2 < NSR) ? delta[(size_t)bh*1024 + gi2] : 0.f;
    }
    for (int ic = 0; ic < iters; ic++) {
      int i0c = j0 + ic*32;
      __syncthreads();
      *(bf16x8*)&Qs[sr*QS + sc]    = rq;
      *(bf16x8*)&DUs[sr*QS + sc]   = rdu;
      *(bf16x8*)&QsT[sr2*TS + sc2]  = rqT;
      *(bf16x8*)&DUsT[sr2*TS + sc2] = rduT;
      if (tid < 32) { mvs[tid] = rm; lvs[tid] = 1.f/rl; dls[tid] = rd; }
      __syncthreads();
      if (ic + 1 < iters) {
        int i1 = i0c + 32;
        int g1 = i1 + sr;
        rq   = *(const bf16x8*)&qb[((size_t)bh*1024 + g1)*64 + sc];
        rdu  = (g1 < NSR) ? *(const bf16x8*)&du_bf[((size_t)b*1024 + g1)*512 + h*64 + sc] : bz8();
        rqT  = *(const bf16x8*)&qbT[((size_t)bh*64 + sr2)*1024 + i1 + sc2];
        rduT = *(const bf16x8*)&duT[((size_t)bh*64 + sr2)*1024 + i1 + sc2];
        if (tid < 32) {
          int gi2 = i1 + tid;
          rm = mrow[(size_t)bh*1024 + gi2];
          rl = lrow[(size_t)bh*1024 + gi2];
          rd = (gi2 < NSR) ? delta[(size_t)bh*1024 + gi2] : 0.f;
        }
      }
      f32x4 st[2] = {fz4(),fz4()};
      f32x4 dt[2] = {fz4(),fz4()};
#pragma unroll
      for (int kc = 0; kc < 64; kc += 32) {
        bf16x8 ak = *(const bf16x8*)&Ks[(w*16 + l15)*QS + kc + quad*8];
        bf16x8 av = *(const bf16x8*)&Vs[(w*16 + l15)*QS + kc + quad*8];
#pragma unroll
        for (int ni = 0; ni < 2; ni++) {
          bf16x8 bq = *(const bf16x8*)&Qs[(ni*16 + l15)*QS + kc + quad*8];
          bf16x8 bd = *(const bf16x8*)&DUs[(ni*16 + l15)*QS + kc + quad*8];
          st[ni] = MFMA16(ak, bq, st[ni]);
          dt[ni] = MFMA16(av, bd, dt[ni]);
        }
      }
#pragma unroll
      for (int ni = 0; ni < 2; ni++)
#pragma unroll
        for (int r = 0; r < 4; r++) {
          int gj = j0 + w*16 + quad*4 + r;
          int il = ni*16 + l15;
          int gi = i0c + il;
          float p = 0.f, dsc = 0.f;
          if (gi >= gj && gi < NSR && gj < NSR) {
            p = __expf(st[ni][r]*0.125f - mvs[il]) * lvs[il];
            dsc = 0.125f*p*(dt[ni][r] - dls[il]);
          }
          int rowp = w*16 + quad*4 + r;
          int pc = ((((ni << 1) | (l15 >> 3)) ^ quad) << 3) | (l15 & 7);
          PsT[rowp*TS + pc] = f2bs(p);
          DsT[rowp*TS + pc] = f2bs(dsc);
        }
      int rc = (quad ^ rsw) << 3;
      bf16x8 ap = *(const bf16x8*)&PsT[(w*16 + l15)*TS + rc];
      bf16x8 ad = *(const bf16x8*)&DsT[(w*16 + l15)*TS + rc];
#pragma unroll
      for (int es = 0; es < 4; es++) {
        bf16x8 bdu = *(const bf16x8*)&DUsT[(es*16 + l15)*TS + quad*8];
        bf16x8 bqt = *(const bf16x8*)&QsT[(es*16 + l15)*TS + quad*8];
        dva[es] = MFMA16(ap, bdu, dva[es]);
        dka[es] = MFMA16(ad, bqt, dka[es]);
      }
    }
#pragma unroll
    for (int r = 0; r < 4; r++) {
      int gj = j0 + w*16 + quad*4 + r;
#pragma unroll
      for (int es = 0; es < 4; es++) {
        dv[((size_t)bh*1024 + gj)*64 + es*16 + l15] = dva[es][r];
        dk[((size_t)bh*1024 + gj)*64 + es*16 + l15] = dka[es][r];
      }
    }
  } else {
    int bid = blockIdx.x - 512;
    int pp = bid >> 8;
    int xx = (bid >> 5) & 7;
    int bh = bid & 31;
    int it = pp ? xx : (15 - xx);
    int i0 = it*64;
    int b = bh >> 3, h = bh & 7;
    short* Qs  = smem;
    short* DUs = Qs + 4608;
    short* Ks  = DUs + 4608;
    short* Vs  = Ks + 2304;
    short* KsT = Vs + 2304;
    short* DsN = KsT + 2560;
    for (int rr = sr; rr < 64; rr += 32) {
      int gi = i0 + rr;
      *(bf16x8*)&Qs[rr*QS + sc] = *(const bf16x8*)&qb[((size_t)bh*1024 + gi)*64 + sc];
      bf16x8 duv = (gi < NSR) ? *(const bf16x8*)&du_bf[((size_t)b*1024 + gi)*512 + h*64 + sc] : bz8();
      *(bf16x8*)&DUs[rr*QS + sc] = duv;
    }
    float m4[4], li4[4], dl4[4];
#pragma unroll
    for (int r = 0; r < 4; r++) {
      int gi = i0 + w*16 + quad*4 + r;
      m4[r]  = mrow[(size_t)bh*1024 + gi];
      li4[r] = 1.f / lrow[(size_t)bh*1024 + gi];
      dl4[r] = (gi < NSR) ? delta[(size_t)bh*1024 + gi] : 0.f;
    }
    f32x4 dqa[4] = {fz4(),fz4(),fz4(),fz4()};
    int jiters = 2*it + 2;
    bf16x8 rk  = *(const bf16x8*)&kb[((size_t)bh*1024 + sr)*64 + sc];
    bf16x8 rv  = *(const bf16x8*)&vb[((size_t)bh*1024 + sr)*64 + sc];
    bf16x8 rkT = *(const bf16x8*)&kbT[((size_t)bh*64 + sr2)*1024 + sc2];
    for (int jc = 0; jc < jiters; jc++) {
      int j0 = jc*32;
      __syncthreads();
      *(bf16x8*)&Ks[sr*QS + sc]    = rk;
      *(bf16x8*)&Vs[sr*QS + sc]    = rv;
      *(bf16x8*)&KsT[sr2*TS + sc2] = rkT;
      __syncthreads();
      if (jc + 1 < jiters) {
        int j1 = j0 + 32;
        rk  = *(const bf16x8*)&kb[((size_t)bh*1024 + j1 + sr)*64 + sc];
        rv  = *(const bf16x8*)&vb[((size_t)bh*1024 + j1 + sr)*64 + sc];
        rkT = *(const bf16x8*)&kbT[((size_t)bh*64 + sr2)*1024 + j1 + sc2];
      }
      f32x4 st[2] = {fz4(),fz4()};
      f32x4 dt[2] = {fz4(),fz4()};
#pragma unroll
      for (int kc = 0; kc < 64; kc += 32) {
        bf16x8 aq = *(const bf16x8*)&Qs[(w*16 + l15)*QS + kc + quad*8];
        bf16x8 adu = *(const bf16x8*)&DUs[(w*16 + l15)*QS + kc + quad*8];
#pragma unroll
        for (int ni = 0; ni < 2; ni++) {
          bf16x8 bk = *(const bf16x8*)&Ks[(ni*16 + l15)*QS + kc + quad*8];
          bf16x8 bv = *(const bf16x8*)&Vs[(ni*16 + l15)*QS + kc + quad*8];
          st[ni] = MFMA16(aq, bk, st[ni]);
          dt[ni] = MFMA16(adu, bv, dt[ni]);
        }
      }
#pragma unroll
      for (int ni = 0; ni < 2; ni++)
#pragma unroll
        for (int r = 0; r < 4; r++) {
          int gi = i0 + w*16 + quad*4 + r;
          int gj = j0 + ni*16 + l15;
          float dsc = 0.f;
          if (gi >= gj && gi < NSR && gj < NSR) {
            float p = __expf(st[ni][r]*0.125f - m4[r]) * li4[r];
            dsc = 0.125f*p*(dt[ni][r] - dl4[r]);
          }
          int rowp = w*16 + quad*4 + r;
          int pc = ((((ni << 1) | (l15 >> 3)) ^ quad) << 3) | (l15 & 7);
          DsN[rowp*TS + pc] = f2bs(dsc);
        }
      bf16x8 ads = *(const bf16x8*)&DsN[(w*16 + l15)*TS + ((quad ^ rsw) << 3)];
#pragma unroll
      for (int es = 0; es < 4; es++) {
        bf16x8 bkt = *(const bf16x8*)&KsT[(es*16 + l15)*TS + quad*8];
        dqa[es] = MFMA16(ads, bkt, dqa[es]);
      }
    }
#pragma unroll
    for (int r = 0; r < 4; r++) {
      int gi = i0 + w*16 + quad*4 + r;
#pragma unroll
      for (int es = 0; es < 4; es++)
        dq[((size_t)bh*1024 + gi)*64 + es*16 + l15] = dqa[es][r];
    }
  }
}

// ---------------- NS phase 1: partial G = X X^T over K-slice + partial sumsq ----------------
__global__ __launch_bounds__(256) void k_ns_g(const float* __restrict__ Xsrc,
                                              float* __restrict__ Gpart, float* __restrict__ sspart) {
  int m = blockIdx.x, s = blockIdx.y;
  const float* Xm = Xsrc + (size_t)m*DH*DD;
  __shared__ __align__(16) short XGhi[64*GS], XGlo[64*GS];
  __shared__ float redz[4];
  int tid = threadIdx.x;
  int lane = tid & 63, w = tid >> 6;
  int l15 = lane & 15, quad = lane >> 4;
  int srow = tid >> 2, scol = (tid & 3)*8;
  int k0 = s*256;
  f32x4 accA[4] = {fz4(),fz4(),fz4(),fz4()};
  float ss = 0.f;
  float4 c1 = *(const float4*)&Xm[(size_t)srow*1024 + k0 + scol];
  float4 c2 = *(const float4*)&Xm[(size_t)srow*1024 + k0 + scol + 4];
  for (int kb = 0; kb < 256; kb += 32) {
    float xv[8] = {c1.x,c1.y,c1.z,c1.w,c2.x,c2.y,c2.z,c2.w};
    bf16x8 hi, lo;
#pragma unroll
    for (int j = 0; j < 8; j++) {
      short h = f2bs(xv[j]);
      hi[j] = h; lo[j] = f2bs(xv[j] - bs2f(h));
      ss += xv[j]*xv[j];
    }
    __syncthreads();
    *(bf16x8*)&XGhi[srow*GS + scol] = hi;
    *(bf16x8*)&XGlo[srow*GS + scol] = lo;
    __syncthreads();
    if (kb + 32 < 256) {
      c1 = *(const float4*)&Xm[(size_t)srow*1024 + k0 + kb + 32 + scol];
      c2 = *(const float4*)&Xm[(size_t)srow*1024 + k0 + kb + 32 + scol + 4];
    }
    bf16x8 ah = *(const bf16x8*)&XGhi[(w*16 + l15)*GS + quad*8];
    bf16x8 al = *(const bf16x8*)&XGlo[(w*16 + l15)*GS + quad*8];
#pragma unroll
    for (int es = 0; es < 4; es++) {
      bf16x8 bh = *(const bf16x8*)&XGhi[(es*16 + l15)*GS + quad*8];
      bf16x8 bl = *(const bf16x8*)&XGlo[(es*16 + l15)*GS + quad*8];
      accA[es] = MFMA16(ah, bh, accA[es]);
      accA[es] = MFMA16(ah, bl, accA[es]);
      accA[es] = MFMA16(al, bh, accA[es]);
    }
  }
  for (int st = 32; st > 0; st >>= 1) ss += __shfl_xor(ss, st, 64);
  if (lane == 0) redz[w] = ss;
  __syncthreads();
  if (tid == 0) sspart[m*4 + s] = redz[0]+redz[1]+redz[2]+redz[3];
  float* Gp = Gpart + (size_t)(m*4 + s)*4096;
#pragma unroll
  for (int es = 0; es < 4; es++)
#pragma unroll
    for (int rr = 0; rr < 4; rr++) {
      int row = w*16 + quad*4 + rr, col = es*16 + l15;
      Gp[row*64 + col] = accA[es][rr];
    }
}

// ---------------- NS phase 2: 5 iterations in 64x64 space -> M5, r ----------------
__global__ __launch_bounds__(256) void k_ns_iter(const float* __restrict__ Gpart, const float* __restrict__ sspart,
                                                 float* __restrict__ M5, float* __restrict__ rbuf) {
  int m = blockIdx.x;
  __shared__ __align__(16) short nsm[46080];
  short* Mhi  = nsm;
  short* Mlo  = nsm + 4608;
  short* MThi = nsm + 2*4608;
  short* MTlo = nsm + 3*4608;
  short* A0hi = nsm + 4*4608;
  short* A0lo = nsm + 5*4608;
  short* Shi  = nsm + 6*4608;
  short* Slo  = nsm + 7*4608;
  short* Aihi = nsm + 8*4608;
  short* Ailo = nsm + 9*4608;
  int tid = threadIdx.x;
  int lane = tid & 63, w = tid >> 6;
  int l15 = lane & 15, quad = lane >> 4;
  float tot = sspart[m*4] + sspart[m*4+1] + sspart[m*4+2] + sspart[m*4+3];
  float r_ = 1.f / (sqrtf(tot) + 1e-7f);
  float r2 = r_ * r_;
  const float* Gp = Gpart + (size_t)(m*4)*4096;
#pragma unroll
  for (int es = 0; es < 4; es++)
#pragma unroll
    for (int rr = 0; rr < 4; rr++) {
      int row = w*16 + quad*4 + rr, col = es*16 + l15;
      int idx = row*64 + col;
      float v = (Gp[idx] + Gp[4096 + idx] + Gp[8192 + idx] + Gp[12288 + idx]) * r2;
      short h = f2bs(v);
      A0hi[row*QS + col] = h;
      A0lo[row*QS + col] = f2bs(v - bs2f(h));
      short ih = (row == col) ? (short)0x3F80 : (short)0;
      Mhi[row*QS + col] = ih;  Mlo[row*QS + col] = 0;
      MThi[row*QS + col] = ih; MTlo[row*QS + col] = 0;
    }
  __syncthreads();
  for (int itn = 0; itn < 5; itn++) {
    f32x4 s4[4] = {fz4(),fz4(),fz4(),fz4()};
    mm64(Mhi, Mlo, A0hi, A0lo, s4, w, l15, quad);
    st_hl(Shi, Slo, s4, w, l15, quad);
    __syncthreads();
    f32x4 ai4[4] = {fz4(),fz4(),fz4(),fz4()};
    mm64(Shi, Slo, Mhi, Mlo, ai4, w, l15, quad);
    st_hl(Aihi, Ailo, ai4, w, l15, quad);
    __syncthreads();
    f32x4 a24[4] = {fz4(),fz4(),fz4(),fz4()};
    mm64(Aihi, Ailo, Aihi, Ailo, a24, w, l15, quad);
    f32x4 b4[4];
#pragma unroll
    for (int es = 0; es < 4; es++) b4[es] = NS_Bc*ai4[es] + NS_Cc*a24[es];
    st_hl(Shi, Slo, b4, w, l15, quad);
    __syncthreads();
    f32x4 m4[4] = {fz4(),fz4(),fz4(),fz4()};
    mm64(Shi, Slo, MThi, MTlo, m4, w, l15, quad);
#pragma unroll
    for (int es = 0; es < 4; es++)
#pragma unroll
      for (int rr = 0; rr < 4; rr++) {
        int row = w*16 + quad*4 + rr, col = es*16 + l15;
        float mold = bs2f(Mhi[row*QS + col]) + bs2f(Mlo[row*QS + col]);
        m4[es][rr] = NS_Ac*mold + m4[es][rr];
      }
    __syncthreads();
#pragma unroll
    for (int es = 0; es < 4; es++)
#pragma unroll
      for (int rr = 0; rr < 4; rr++) {
        int row = w*16 + quad*4 + rr, col = es*16 + l15;
        float x = m4[es][rr];
        short h = f2bs(x);
        short lo = f2bs(x - bs2f(h));
        Mhi[row*QS + col] = h;  Mlo[row*QS + col] = lo;
        MThi[col*QS + row] = h; MTlo[col*QS + row] = lo;
      }
    __syncthreads();
  }
#pragma unroll
  for (int es = 0; es < 4; es++)
#pragma unroll
    for (int rr = 0; rr < 4; rr++) {
      int row = w*16 + quad*4 + rr, col = es*16 + l15;
      M5[(size_t)m*4096 + row*64 + col] = bs2f(Mhi[row*QS + col]) + bs2f(Mlo[row*QS + col]);
    }
  if (tid == 0) rbuf[m] = r_;
}

// ---------------- NS phase 3: apply Y = r*(M5 X) + fused output ----------------
__global__ __launch_bounds__(256) void k_ns_apply(const float* __restrict__ Xsrc, const float* __restrict__ M5,
                                                  const float* __restrict__ rbuf, void* __restrict__ d_outv,
                                                  size_t off_dwv, size_t off_dwo, const int* __restrict__ flag) {
  int m = blockIdx.x, cs = blockIdx.y;
  const float* Xm = Xsrc + (size_t)m*DH*DD;
  const int f = *flag;
  float r_ = rbuf[m];
  __shared__ __align__(16) short Mhi[4608], Mlo[4608], XThi[4608], XTlo[4608];
  __shared__ float Sf[64*65];
  int tid = threadIdx.x;
  int lane = tid & 63, w = tid >> 6;
  int l15 = lane & 15, quad = lane >> 4;
  int srow = tid >> 2, scol = (tid & 3)*8;
  for (int i = tid; i < 4096; i += 256) {
    float v = M5[(size_t)m*4096 + i];
    int rowi = i >> 6, coli = i & 63;
    short h = f2bs(v);
    Mhi[rowi*QS + coli] = h;
    Mlo[rowi*QS + coli] = f2bs(v - bs2f(h));
  }
  int cbase = cs*256;
  float4 d1 = *(const float4*)&Xm[(size_t)srow*1024 + cbase + scol];
  float4 d2 = *(const float4*)&Xm[(size_t)srow*1024 + cbase + scol + 4];
  float4 d3 = *(const float4*)&Xm[(size_t)srow*1024 + cbase + scol + 32];
  float4 d4 = *(const float4*)&Xm[(size_t)srow*1024 + cbase + scol + 36];
  for (int cc = 0; cc < 256; cc += 64) {
    int c0 = cbase + cc;
    __syncthreads();
    {
      float xv0[8] = {d1.x,d1.y,d1.z,d1.w,d2.x,d2.y,d2.z,d2.w};
      float xv1[8] = {d3.x,d3.y,d3.z,d3.w,d4.x,d4.y,d4.z,d4.w};
#pragma unroll
      for (int j = 0; j < 8; j++) {
        int n0 = scol + j;
        short h0 = f2bs(xv0[j]);
        XThi[n0*QS + srow] = h0;
        XTlo[n0*QS + srow] = f2bs(xv0[j] - bs2f(h0));
        int n1 = scol + 32 + j;
        short h1 = f2bs(xv1[j]);
        XThi[n1*QS + srow] = h1;
        XTlo[n1*QS + srow] = f2bs(xv1[j] - bs2f(h1));
      }
    }
    __syncthreads();
    if (cc + 64 < 256) {
      d1 = *(const float4*)&Xm[(size_t)srow*1024 + c0 + 64 + scol];
      d2 = *(const float4*)&Xm[(size_t)srow*1024 + c0 + 64 + scol + 4];
      d3 = *(const float4*)&Xm[(size_t)srow*1024 + c0 + 64 + scol + 32];
      d4 = *(const float4*)&Xm[(size_t)srow*1024 + c0 + 64 + scol + 36];
    }
    f32x4 u4[4] = {fz4(),fz4(),fz4(),fz4()};
    mm64(Mhi, Mlo, XThi, XTlo, u4, w, l15, quad);
    if (m >= 32) {
#pragma unroll
      for (int es = 0; es < 4; es++)
#pragma unroll
        for (int rr = 0; rr < 4; rr++) {
          int row = w*16 + quad*4 + rr, col = c0 + es*16 + l15;
          stout(d_outv, off_dwo + (size_t)(m-32)*65536 + (size_t)row*1024 + col, r_*u4[es][rr], f);
        }
    } else {
#pragma unroll
      for (int es = 0; es < 4; es++)
#pragma unroll
        for (int rr = 0; rr < 4; rr++) {
          int row = w*16 + quad*4 + rr, col = es*16 + l15;
          Sf[col*65 + row] = r_*u4[es][rr];
        }
      __syncthreads();
      int dl = tid >> 2, e0 = (tid & 3)*16;
      size_t ob = off_dwv + (size_t)m*65536 + (size_t)(c0 + dl)*64 + e0;
#pragma unroll
      for (int j = 0; j < 16; j++)
        stout(d_outv, ob + j, Sf[dl*65 + e0 + j], f);
    }
  }
}

extern "C" void kernel_launch(void* const* d_in, const int* in_sizes, int n_in,
                              void* d_out, int out_size, void* d_ws, size_t ws_size,
                              hipStream_t stream) {
  const void* tokens   = d_in[0];
  const void* wq       = d_in[1];
  const void* wk       = d_in[2];
  const void* wv       = d_in[3];
  const void* wo       = d_in[4];
  const void* w_lr     = d_in[5];
  const void* w_target = d_in[6];
  const void* w_gates  = d_in[7];
  const void* rms_w    = d_in[8];

  const size_t off_dwq  = 4194304;
  const size_t off_dwk  = 6291456;
  const size_t off_dwv  = 8388608;
  const size_t off_dwo  = 10485760;

  float* ws = (float*)d_ws;
  float* t_    = ws;
  float* tvbuf = ws;
  short* errT  = (short*)ws;
  short* oT    = (short*)(ws + 2097152);
  short* t_bf  = (short*)(ws + 4194304);
  short* err_bf= (short*)(ws + 4194304);
  short* tT    = (short*)(ws + 6291456);
  short* qb    = (short*)(ws + 8388608);
  short* kbuf  = qb + 2097152;
  short* vbuf  = qb + 4194304;
  short* dqT   = (short*)(ws + 8388608);
  short* dkT   = dqT + 2097152;
  short* dvT   = dqT + 4194304;
  float* o_    = ws + 11534336;
  short* o_bf  = (short*)(ws + 13631488);
  short* du_bf = (short*)(ws + 13631488);
  float* predf = ws + 14680064;
  float* Xns   = ws + 14680064;
  short* BqkvT = (short*)(ws + 18874368);
  short* wtT   = (short*)(ws + 19660800);
  short* woT2  = (short*)(ws + 20185088);
  short* wo_bf = (short*)(ws + 20447232);
  float* gw    = ws + 20709376;
  float* lrw   = ws + 20717568;
  float* rms_f = ws + 20719616;
  float* dv_   = ws + 18874368;
  float* dk_   = ws + 20971520;
  float* dq_   = ws + 23068672;
  float* gates_= ws + 25165824;
  float* mrow_ = ws + 25198592;
  float* lrow_ = ws + 25231360;
  float* delta_= ws + 25264128;
  float* lr_   = ws + 25296896;
  float* mlr_  = ws + 25300992;
  int*   flag_ = (int*)(ws + 25305088);
  // transposed attention operands (time-multiplexed dead regions):
  short* vbT = (short*)(ws + 3145728);
  short* duT = (short*)(ws + 3145728);
  short* kbT = (short*)(ws + 4194304);
  short* qbT = (short*)ws;
  // NS scratch (dead regions): Gpart dv_/BqkvT area; M5b wtT area; rbuf/sspart woT2 area
  float* Gpart  = ws + 18874368;
  float* M5b    = ws + 19922944;
  float* rbuf   = ws + 20185088;
  float* sspart = ws + 20185152;

  hipLaunchKernelGGL(k_prep, dim3(1324 + BB*NN), dim3(256), 0, stream, wq, wk, wv, w_target, wo, w_lr, w_gates, rms_w,
                     BqkvT, wtT, woT2, wo_bf, lrw, gw, rms_f, flag_,
                     tokens, t_, t_bf, gates_, lr_, mlr_);
  hipLaunchKernelGGL(k_transp, dim3(64,16,1), dim3(256), 0, stream, t_, (size_t)0, 1024, tT, (size_t)0, 4096, (const float*)nullptr, 0, 4096);

  hipLaunchKernelGGL(k_gemm2, dim3(32,12), dim3(256), 0, stream, t_bf, BqkvT, 1024, 1024, 1024, 4096, 0, 0,
                     (float*)nullptr, qb, (void*)nullptr, vbT, (const float*)nullptr, flag_,
                     0, (const short*)nullptr, (const short*)nullptr, 0, 0, 0, 0, 0, 0, (float*)nullptr, (void*)nullptr);
  hipLaunchKernelGGL(k_attn_fwd, dim3(512), dim3(256), 0, stream, qb, kbuf, vbT, gates_, o_, o_bf, mrow_, lrow_);
  // fused ep1 (y<8: pred) + ep2 (y>=8: tv)
  hipLaunchKernelGGL(k_gemm2, dim3(32,16), dim3(256), 0, stream, o_bf, woT2, 512, 512, 512, 4096, 0, 1,
                     predf, (short*)nullptr, d_out, (short*)nullptr, (const float*)nullptr, flag_,
                     8, t_bf, wtT, 1024, 1024, 1024, 4092, 1, 2, tvbuf, (void*)nullptr);
  hipLaunchKernelGGL(k_lnsub, dim3(BB*NSR), dim3(256), 0, stream, tvbuf, predf, err_bf);
  hipLaunchKernelGGL(k_gemm2, dim3(32,4), dim3(256), 0, stream, err_bf, wo_bf, 1024, 1024, 1024, 4092, 2, 3,
                     (float*)nullptr, du_bf, (void*)nullptr, (short*)nullptr, gates_, flag_,
                     0, (const short*)nullptr, (const short*)nullptr, 0, 0, 0, 0, 0, 0, (float*)nullptr, (void*)nullptr);
  hipLaunchKernelGGL(k_t16, dim3(1536 + BB*NSR), dim3(256), 0, stream, (const short*)qb, (const short*)du_bf,
                     kbT, duT, qbT, o_, gates_, delta_);
  hipLaunchKernelGGL(k_bwd, dim3(1024), dim3(256), 0, stream, qb, kbuf, vbuf, du_bf, qbT, duT, kbT,
                     mrow_, lrow_, delta_, dv_, dk_, dq_);
  hipLaunchKernelGGL(k_transp5, dim3(3072), dim3(256), 0, stream, dq_, dk_, dv_, predf, o_,
                     dqT, dkT, dvT, errT, oT, lr_, mlr_);
  hipLaunchKernelGGL(k_gemm_bf, dim3(16,1,64), dim3(256), 0, stream, tT, dqT, 4096, 1024, 1024, 1024, 0, 4,
                     (size_t)0,(size_t)1024,(size_t)65536,(size_t)0, (float*)nullptr, (short*)nullptr, d_out, off_dwq,
                     (const float*)nullptr, flag_, (const short*)nullptr, (const short*)dkT, (size_t)0, off_dwk, 1024);
  hipLaunchKernelGGL(k_gemm_bf, dim3(1,16,64), dim3(256), 0, stream, dvT, tT, 1024, 4096, 1024, 64, 0, 5,
                     (size_t)65536,(size_t)0,(size_t)0,(size_t)1024, Xns, (short*)nullptr, (void*)nullptr, (size_t)0,
                     (const float*)nullptr, flag_, (const short*)oT, (const short*)errT, (size_t)1048576, (size_t)0, 1024);
  hipLaunchKernelGGL(k_ns_g,     dim3(64,4), dim3(256), 0, stream, Xns, Gpart, sspart);
  hipLaunchKernelGGL(k_ns_iter,  dim3(64),   dim3(256), 0, stream, Gpart, sspart, M5b, rbuf);
  hipLaunchKernelGGL(k_ns_apply, dim3(64,4), dim3(256), 0, stream, Xns, M5b, rbuf, d_out, off_dwv, off_dwo, flag_);
  (void)in_sizes; (void)n_in; (void)out_size; (void)ws_size;
}

// Round 12
// 444.815 us; speedup vs baseline: 1.2371x; 1.2371x over previous
//
#include <hip/hip_runtime.h>
#include <hip/hip_bf16.h>
#include <math.h>

#define BB 4
#define NN 1024
#define DD 1024
#define HH 8
#define DH 64
#define NSR 1023

#define NS_Ac 3.4445f
#define NS_Bc (-4.775f)
#define NS_Cc 2.0315f

typedef short bf16x8 __attribute__((ext_vector_type(8)));
typedef float f32x4 __attribute__((ext_vector_type(4)));
#define MFMA16(a,b,c) __builtin_amdgcn_mfma_f32_16x16x32_bf16(a,b,c,0,0,0)

#define QS 72   // LDS row stride (bf16) for [rows][64] tiles
#define TS 40   // LDS row stride (bf16) for [rows][32] tiles
#define GS 40   // GEMM LDS row stride (bf16) for [64][32] tiles

static __device__ __forceinline__ float ldin(const void* p, size_t i, int f) {
  return f ? ((const float*)p)[i] : __bfloat162float(((const __hip_bfloat16*)p)[i]);
}
static __device__ __forceinline__ void stout(void* p, size_t i, float v, int f) {
  if (f) ((float*)p)[i] = v;
  else   ((__hip_bfloat16*)p)[i] = __float2bfloat16(v);
}
static __device__ __forceinline__ short f2bs(float x) {
  union { float f; unsigned u; } a; a.f = x;
  unsigned r = a.u + 0x7fffu + ((a.u >> 16) & 1u);
  return (short)(r >> 16);
}
static __device__ __forceinline__ float bs2f(short s) {
  union { unsigned u; float f; } a; a.u = ((unsigned)(unsigned short)s) << 16;
  return a.f;
}
static __device__ __forceinline__ f32x4 fz4() { f32x4 z = {0.f,0.f,0.f,0.f}; return z; }
static __device__ __forceinline__ bf16x8 bz8() { bf16x8 z = {0,0,0,0,0,0,0,0}; return z; }

// 64x64 split-bf16 matmul: C += A * B^T (A,B row-major [64][QS] hi/lo pairs in LDS)
static __device__ __forceinline__ void mm64(const short* __restrict__ Ah, const short* __restrict__ Al,
                                            const short* __restrict__ Bh, const short* __restrict__ Bl,
                                            f32x4* acc, int w, int l15, int quad) {
#pragma unroll
  for (int kc = 0; kc < 64; kc += 32) {
    bf16x8 ah = *(const bf16x8*)&Ah[(w*16 + l15)*QS + kc + quad*8];
    bf16x8 al = *(const bf16x8*)&Al[(w*16 + l15)*QS + kc + quad*8];
#pragma unroll
    for (int es = 0; es < 4; es++) {
      bf16x8 bh = *(const bf16x8*)&Bh[(es*16 + l15)*QS + kc + quad*8];
      bf16x8 bl = *(const bf16x8*)&Bl[(es*16 + l15)*QS + kc + quad*8];
      acc[es] = MFMA16(ah, bh, acc[es]);
      acc[es] = MFMA16(ah, bl, acc[es]);
      acc[es] = MFMA16(al, bh, acc[es]);
    }
  }
}
// write fragment (fp32) as hi/lo bf16 pair at output coords
static __device__ __forceinline__ void st_hl(short* __restrict__ Dh, short* __restrict__ Dl,
                                             const f32x4* v, int w, int l15, int quad) {
#pragma unroll
  for (int es = 0; es < 4; es++)
#pragma unroll
    for (int rr = 0; rr < 4; rr++) {
      int row = w*16 + quad*4 + rr, col = es*16 + l15;
      float x = v[es][rr];
      short h = f2bs(x);
      Dh[row*QS + col] = h;
      Dl[row*QS + col] = f2bs(x - bs2f(h));
    }
}

// ---------------- fused prep: all weight converters + small tensors + flag ----------------
__global__ __launch_bounds__(256) void k_prep(
    const void* wq, const void* wk, const void* wv,
    const void* w_target, const void* wo, const void* w_lr, const void* w_gates, const void* rms_w,
    short* __restrict__ BqkvT, short* __restrict__ wtT, short* __restrict__ woT2,
    short* __restrict__ wo_bf, float* __restrict__ lrw, float* __restrict__ gw,
    float* __restrict__ rms_f, int* __restrict__ flag)
{
  const int f = (((const unsigned short*)rms_w)[0] == 0x3F80) ? 0 : 1;
  int bx = blockIdx.x; int tid = threadIdx.x;
  if (bx >= 768) {
    if (bx < 812) {
      if (bx == 768 && tid == 0) *flag = f;
      int idx = (bx - 768)*256 + tid;
      if (idx < 2048) lrw[idx] = ldin(w_lr, idx, f);
      else if (idx < 10240) gw[idx-2048] = ldin(w_gates, idx-2048, f);
      else if (idx < 11264) rms_f[idx-10240] = ldin(rms_w, idx-10240, f);
    } else {
      size_t base = (size_t)(bx - 812)*1024;
#pragma unroll
      for (int j = 0; j < 4; j++) {
        size_t i2 = base + tid + 256*j;
        wo_bf[i2] = f2bs(ldin(wo, i2, f));
      }
    }
    return;
  }
  const void* src; short* dst; int sld, dld, srow0, scol0, drow0; size_t soff = 0;
  if (bx < 384) {
    int x = bx & 15, y = bx >> 4;
    int n0 = y*64; int which = n0 >> 9, h = (n0 >> 6) & 7;
    src = (which==0) ? wq : (which==1) ? wk : wv;
    soff = (size_t)h*65536;
    sld = 64; dld = 1024; srow0 = x*64; scol0 = 0; drow0 = n0; dst = BqkvT;
  } else if (bx < 640) {
    int r = bx - 384; int x = r & 15, y = r >> 4;
    src = w_target; dst = wtT; sld = 1024; dld = 1024;
    srow0 = x*64; scol0 = y*64; drow0 = scol0;
  } else {
    int r = bx - 640; int x = r & 7, y = r >> 3;
    src = wo; dst = woT2; sld = 1024; dld = 512;
    srow0 = x*64; scol0 = y*64; drow0 = scol0;
  }
  __shared__ float T[64][65];
  int r4 = tid >> 4, c4 = (tid & 15)*4;
  for (int rr = r4; rr < 64; rr += 16)
#pragma unroll
    for (int j = 0; j < 4; j++)
      T[rr][c4+j] = ldin(src, soff + (size_t)(srow0+rr)*sld + scol0 + c4 + j, f);
  __syncthreads();
  int dc = tid >> 2, seg = tid & 3;
  bf16x8 o1, o2;
#pragma unroll
  for (int j = 0; j < 8; j++) { o1[j] = f2bs(T[seg*16+j][dc]); o2[j] = f2bs(T[seg*16+8+j][dc]); }
  *(bf16x8*)&dst[(size_t)(drow0+dc)*dld + srow0 + seg*16]     = o1;
  *(bf16x8*)&dst[(size_t)(drow0+dc)*dld + srow0 + seg*16 + 8] = o2;
}

// ---------------- RMSNorm fused with gates + lr/mlr (reads converted gw/lrw/rms_f) ----------------
__global__ void k_rmsnorm(const void* __restrict__ tokens, const float* __restrict__ rms_f,
                          const float* __restrict__ gw, const float* __restrict__ lrw,
                          float* __restrict__ t, short* __restrict__ t_bf,
                          float* __restrict__ gates, float* __restrict__ lr, float* __restrict__ mlr,
                          const int* __restrict__ flag) {
  const int f = *flag;
  int row = blockIdx.x;
  int b = row >> 10, n = row & 1023;
  __shared__ float red[256];
  __shared__ float red2[4][10];
  float xv[4]; float acc = 0.f;
#pragma unroll
  for (int i = 0; i < 4; i++) {
    xv[i] = ldin(tokens, (size_t)row*DD + threadIdx.x + 256*i, f);
    acc += xv[i]*xv[i];
  }
  red[threadIdx.x] = acc; __syncthreads();
  for (int s = 128; s > 0; s >>= 1) { if (threadIdx.x < s) red[threadIdx.x] += red[threadIdx.x+s]; __syncthreads(); }
  float r = rsqrtf(red[0] / DD + 1.1920929e-07f);
  float a10[10] = {0,0,0,0,0,0,0,0,0,0};
#pragma unroll
  for (int i = 0; i < 4; i++) {
    int d = threadIdx.x + 256*i;
    float v = xv[i] * r * rms_f[d];
    t[(size_t)row*DD + d] = v;
    t_bf[(size_t)row*DD + d] = f2bs(v);
#pragma unroll
    for (int h = 0; h < HH; h++) a10[h] += v * gw[d*HH + h];
    a10[8] += v * lrw[d*2];
    a10[9] += v * lrw[d*2+1];
  }
  int lane = threadIdx.x & 63, w = threadIdx.x >> 6;
#pragma unroll
  for (int c = 0; c < 10; c++) {
    float a = a10[c];
    for (int s = 32; s > 0; s >>= 1) a += __shfl_xor(a, s, 64);
    if (lane == 0) red2[w][c] = a;
  }
  __syncthreads();
  if (threadIdx.x < 10) {
    int c = threadIdx.x;
    float sum = red2[0][c]+red2[1][c]+red2[2][c]+red2[3][c];
    float sg = 1.f / (1.f + __expf(-sum));
    if (c < 8)      gates[((size_t)b*HH + c)*NN + n] = sg;
    else if (c == 8) lr[row]  = sg * 0.01f;
    else             mlr[row] = sg * 0.01f;
  }
}

// fp32 [R][C] -> bf16 [C][R] (kept for the t->tT transpose)
__global__ __launch_bounds__(256) void k_transp(
    const float* __restrict__ src, size_t sStepZ, int sld,
    short* __restrict__ dst, size_t dStepZ, int dld,
    const float* __restrict__ coef, int zIsBh, int nz)
{
  int z = blockIdx.z;
  const float* sb = src + (size_t)z*sStepZ;
  short* db = dst + (size_t)z*dStepZ;
  const float* cb = coef ? coef + (size_t)(zIsBh ? (z>>3) : z)*1024 : (const float*)0;
  int x0 = blockIdx.x*64, y0 = blockIdx.y*64;
  __shared__ float T[64][65];
  int tid = threadIdx.x;
  int r4 = tid >> 4, c4 = (tid & 15)*4;
  for (int rr = r4; rr < 64; rr += 16) {
    int rg = x0 + rr;
    bool val = rg < nz;
    float cf = val ? (cb ? cb[rg] : 1.f) : 0.f;
    float4 v = val ? *(const float4*)&sb[(size_t)rg*sld + y0 + c4] : make_float4(0,0,0,0);
    T[rr][c4+0] = v.x*cf; T[rr][c4+1] = v.y*cf; T[rr][c4+2] = v.z*cf; T[rr][c4+3] = v.w*cf;
  }
  __syncthreads();
  int dc = tid >> 2, seg = tid & 3;
  bf16x8 o1, o2;
#pragma unroll
  for (int j = 0; j < 8; j++) { o1[j] = f2bs(T[seg*16+j][dc]); o2[j] = f2bs(T[seg*16+8+j][dc]); }
  *(bf16x8*)&db[(size_t)(y0+dc)*dld + x0 + seg*16]     = o1;
  *(bf16x8*)&db[(size_t)(y0+dc)*dld + x0 + seg*16 + 8] = o2;
}

// ---------------- 5-way fused fp32->bf16T transposes (post-bwd) ----------------
__global__ __launch_bounds__(256) void k_transp5(
    const float* __restrict__ dq, const float* __restrict__ dk, const float* __restrict__ dv,
    const float* __restrict__ predf, const float* __restrict__ o,
    short* __restrict__ dqT, short* __restrict__ dkT, short* __restrict__ dvT,
    short* __restrict__ errT, short* __restrict__ oT,
    const float* __restrict__ lr, const float* __restrict__ mlr)
{
  int bx = blockIdx.x;
  const float* src; short* dst; const float* cb; int sld, dld, x0, y0;
  size_t sStep, dStep; int z;
  if (bx < 1536) {
    int which = bx >> 9; int r = bx & 511;
    z = r >> 4; x0 = (r & 15)*64; y0 = 0;
    sld = 64; dld = 1024; sStep = 65536; dStep = 65536;
    if (which == 0)      { src = dq; dst = dqT; cb = lr; }
    else if (which == 1) { src = dk; dst = dkT; cb = lr; }
    else                 { src = dv; dst = dvT; cb = mlr; }
    cb += (size_t)(z >> 3)*1024;
  } else if (bx < 2560) {
    int r = bx - 1536; z = r >> 8; x0 = (r & 15)*64; y0 = ((r >> 4) & 15)*64;
    src = predf; dst = errT; cb = (const float*)0;
    sld = 1024; dld = 1024; sStep = 1048576; dStep = 1048576;
  } else {
    int r = bx - 2560; z = r >> 7; x0 = (r & 15)*64; y0 = ((r >> 4) & 7)*64;
    src = o; dst = oT; cb = mlr + (size_t)z*1024;
    sld = 512; dld = 1024; sStep = 524288; dStep = 524288;
  }
  src += (size_t)z*sStep; dst += (size_t)z*dStep;
  __shared__ float T[64][65];
  int tid = threadIdx.x;
  int r4 = tid >> 4, c4 = (tid & 15)*4;
  for (int rr = r4; rr < 64; rr += 16) {
    int rg = x0 + rr;
    bool val = rg < 1023;
    float cf = val ? (cb ? cb[rg] : 1.f) : 0.f;
    float4 v = val ? *(const float4*)&src[(size_t)rg*sld + y0 + c4] : make_float4(0,0,0,0);
    T[rr][c4+0] = v.x*cf; T[rr][c4+1] = v.y*cf; T[rr][c4+2] = v.z*cf; T[rr][c4+3] = v.w*cf;
  }
  __syncthreads();
  int dc = tid >> 2, seg = tid & 3;
  bf16x8 o1, o2;
#pragma unroll
  for (int j = 0; j < 8; j++) { o1[j] = f2bs(T[seg*16+j][dc]); o2[j] = f2bs(T[seg*16+8+j][dc]); }
  *(bf16x8*)&dst[(size_t)(y0+dc)*dld + x0 + seg*16]     = o1;
  *(bf16x8*)&dst[(size_t)(y0+dc)*dld + x0 + seg*16 + 8] = o2;
}

// ---------------- 128x128 MFMA GEMM (big shapes): C[M x N] = A[M][K] * B^T ----------------
// Dual-mode: blocks with blockIdx.y >= ysplit use the second parameter set (fused launches).
__global__ __launch_bounds__(256) void k_gemm2(
    const short* __restrict__ A, const short* __restrict__ B,
    int lda, int ldb, int K, int M, int rowmode, int ep,
    float* __restrict__ O0, short* __restrict__ OS, void* __restrict__ OD,
    short* __restrict__ VT, const float* __restrict__ gates, const int* __restrict__ flag,
    int ysplit, const short* __restrict__ A2, const short* __restrict__ B2,
    int lda2, int ldb2, int K2, int M2, int rowmode2, int ep2p,
    float* __restrict__ O02, void* __restrict__ OD2)
{
  int yb = blockIdx.y;
  const short* Au = A; const short* Bu = B;
  int ldav = lda, ldbv = ldb, Kv = K, Mv = M, rmv = rowmode, epv = ep;
  float* O0v = O0; void* ODv = OD;
  if (ysplit && yb >= ysplit) {
    yb -= ysplit; Au = A2; Bu = B2; ldav = lda2; ldbv = ldb2; Kv = K2; Mv = M2;
    rmv = rowmode2; epv = ep2p; O0v = O02; ODv = OD2;
  }
  int m0 = blockIdx.x*128, n0 = yb*128;
  __shared__ __align__(16) short sm2[17408];
  short* As = sm2;          // 128*GS = 5120
  short* Bs = sm2 + 5120;   // 5120
  int tid = threadIdx.x;
  int lane = tid & 63, w = tid >> 6;
  int wr = w >> 1, wc = w & 1;
  int l15 = lane & 15, quad = lane >> 4;
  int row = tid >> 1, col16 = (tid & 1)*16;
  int r = m0 + row;
  int arow;
  if (rmv == 1)      { int b = r / 1023; arow = r + b + 1; }
  else if (rmv == 2) { int b = r / 1023; arow = r + b; }
  else arow = r;
  bool aval = (r < Mv);
  const short* Ap = Au + (size_t)arow*ldav + col16;
  const short* Bp = Bu + (size_t)(n0+row)*ldbv + col16;
  f32x4 acc[4][4];
#pragma unroll
  for (int mi = 0; mi < 4; mi++)
#pragma unroll
    for (int ni = 0; ni < 4; ni++) acc[mi][ni] = fz4();
  bf16x8 av0 = aval ? *(const bf16x8*)(Ap) : bz8();
  bf16x8 av1 = aval ? *(const bf16x8*)(Ap + 8) : bz8();
  bf16x8 bv0 = *(const bf16x8*)(Bp);
  bf16x8 bv1 = *(const bf16x8*)(Bp + 8);
  for (int kb = 0; kb < Kv; kb += 32) {
    __syncthreads();
    *(bf16x8*)&As[row*GS + col16]     = av0;
    *(bf16x8*)&As[row*GS + col16 + 8] = av1;
    *(bf16x8*)&Bs[row*GS + col16]     = bv0;
    *(bf16x8*)&Bs[row*GS + col16 + 8] = bv1;
    __syncthreads();
    if (kb + 32 < Kv) {
      av0 = aval ? *(const bf16x8*)(Ap + kb + 32) : bz8();
      av1 = aval ? *(const bf16x8*)(Ap + kb + 40) : bz8();
      bv0 = *(const bf16x8*)(Bp + kb + 32);
      bv1 = *(const bf16x8*)(Bp + kb + 40);
    }
    bf16x8 afr[4], bfr[4];
#pragma unroll
    for (int mi = 0; mi < 4; mi++)
      afr[mi] = *(const bf16x8*)&As[(wr*64 + mi*16 + l15)*GS + quad*8];
#pragma unroll
    for (int ni = 0; ni < 4; ni++)
      bfr[ni] = *(const bf16x8*)&Bs[(wc*64 + ni*16 + l15)*GS + quad*8];
#pragma unroll
    for (int mi = 0; mi < 4; mi++)
#pragma unroll
      for (int ni = 0; ni < 4; ni++)
        acc[mi][ni] = MFMA16(afr[mi], bfr[ni], acc[mi][ni]);
  }
  const int f = flag ? *flag : 1;
#pragma unroll
  for (int mi = 0; mi < 4; mi++)
#pragma unroll
    for (int ni = 0; ni < 4; ni++)
#pragma unroll
      for (int rix = 0; rix < 4; rix++) {
        int rr = m0 + wr*64 + mi*16 + quad*4 + rix;
        if (rr >= Mv) continue;
        int c = n0 + wc*64 + ni*16 + l15;
        float val = acc[mi][ni][rix];
        if (epv == 0) {
          int which = c >> 9; int h = (c >> 6) & 7; int e = c & 63;
          int b = rr >> 10; int n = rr & 1023;
          OS[(size_t)which*2097152 + (((size_t)b*8 + h)*1024 + n)*64 + e] = f2bs(val);
        } else if (epv == 1) {
          O0v[(size_t)rr*1024 + c] = val;
          stout(ODv, (size_t)rr*1024 + c, val, f);
        } else if (epv == 2) {
          O0v[(size_t)rr*1024 + c] = val;
        } else {
          int b = rr / 1023; int n = rr % 1023;
          int h = c >> 6;
          float g = gates[((size_t)b*8 + h)*1024 + n];
          OS[((size_t)b*1024 + n)*512 + c] = f2bs(val * g);
        }
      }
  // ep0: v-tiles (c in [1024,1536)) additionally write transposed vbT via LDS stage
  if (epv == 0 && n0 >= 1024) {
    short* ST = sm2;   // [128 c][136: m 0..63 at 0, m 64..127 at 72]
    __syncthreads();
#pragma unroll
    for (int mi = 0; mi < 4; mi++)
#pragma unroll
      for (int ni = 0; ni < 4; ni++)
#pragma unroll
        for (int rix = 0; rix < 4; rix++) {
          int ml = wr*64 + mi*16 + quad*4 + rix;
          int cl = wc*64 + ni*16 + l15;
          int mo = ml + ((ml >> 6) << 3);   // +8 if ml>=64
          ST[cl*136 + mo] = f2bs(acc[mi][ni][rix]);
        }
    __syncthreads();
    int r2 = tid >> 1;
    int sg = tid & 1;
    int cg = n0 + r2;
    int h = (cg >> 6) & 7;
    int e = cg & 63;
    int b = m0 >> 10;
    int bh = b*8 + h;
    size_t dst = ((size_t)bh*64 + e)*1024 + (m0 & 1023) + sg*64;
    int so = r2*136 + sg*72;
#pragma unroll
    for (int j = 0; j < 64; j += 8)
      *(bf16x8*)&VT[dst + j] = *(const bf16x8*)&ST[so + j];
  }
}

// ---------------- universal MFMA GEMM (64x64, K-step 64): kept for ep4/ep5 fused shapes ----------------
__global__ __launch_bounds__(256) void k_gemm_bf(
    const short* __restrict__ A, const short* __restrict__ B,
    int lda, int ldb, int K, int M, int rowmode, int ep,
    size_t aStepBh, size_t aStepB, size_t bStepBh, size_t bStepB,
    float* __restrict__ O0, short* __restrict__ OS, void* __restrict__ OD,
    size_t out_off, const float* __restrict__ gates, const int* __restrict__ flag,
    const short* __restrict__ A2, const short* __restrict__ B2,
    size_t bStepB2, size_t out_off2, int ldb2)
{
  int z = blockIdx.z;
  const short* Au = A; const short* Bu = B;
  size_t bStepBv = bStepB; size_t out_offv = out_off;
  int epv = ep; int ldbv = ldb;
  if (ep == 4 && z >= 32) { Bu = B2; out_offv = out_off2; z -= 32; }
  if (ep == 5 && z >= 32) { Au = A2; Bu = B2; bStepBv = bStepB2; ldbv = ldb2; epv = 6; z -= 32; }
  int zb = z >> 3;
  const short* Ab = Au + (size_t)z*aStepBh + (size_t)zb*aStepB;
  const short* Bb = Bu + (size_t)z*bStepBh + (size_t)zb*bStepBv;
  int m0 = blockIdx.x*64, n0 = blockIdx.y*64;
  __shared__ __align__(16) short AsBs[9216];
  short* As = AsBs;
  short* Bs = AsBs + 4608;
  int tid = threadIdx.x;
  int lane = tid & 63, w = tid >> 6;
  int l15 = lane & 15, quad = lane >> 4;
  int row = tid >> 2, col16 = (tid & 3)*16;
  int r = m0 + row;
  int arow;
  if (rowmode == 1)      { int b = r / 1023; arow = r + b + 1; }
  else if (rowmode == 2) { int b = r / 1023; arow = r + b; }
  else arow = r;
  bool aval = (r < M);
  const short* Ap = Ab + (size_t)arow*lda + col16;
  const short* Bp = Bb + (size_t)(n0+row)*ldbv + col16;
  f32x4 acc[4] = {fz4(),fz4(),fz4(),fz4()};
  bf16x8 av0 = aval ? *(const bf16x8*)(Ap) : bz8();
  bf16x8 av1 = aval ? *(const bf16x8*)(Ap + 8) : bz8();
  bf16x8 bv0 = *(const bf16x8*)(Bp);
  bf16x8 bv1 = *(const bf16x8*)(Bp + 8);
  for (int kb = 0; kb < K; kb += 64) {
    __syncthreads();
    *(bf16x8*)&As[row*QS + col16]     = av0;
    *(bf16x8*)&As[row*QS + col16 + 8] = av1;
    *(bf16x8*)&Bs[row*QS + col16]     = bv0;
    *(bf16x8*)&Bs[row*QS + col16 + 8] = bv1;
    __syncthreads();
    if (kb + 64 < K) {
      av0 = aval ? *(const bf16x8*)(Ap + kb + 64) : bz8();
      av1 = aval ? *(const bf16x8*)(Ap + kb + 72) : bz8();
      bv0 = *(const bf16x8*)(Bp + kb + 64);
      bv1 = *(const bf16x8*)(Bp + kb + 72);
    }
#pragma unroll
    for (int kc = 0; kc < 64; kc += 32) {
      bf16x8 afr = *(const bf16x8*)&As[(w*16 + l15)*QS + kc + quad*8];
#pragma unroll
      for (int es = 0; es < 4; es++) {
        bf16x8 bfr = *(const bf16x8*)&Bs[(es*16 + l15)*QS + kc + quad*8];
        acc[es] = MFMA16(afr, bfr, acc[es]);
      }
    }
  }
  const int f = flag ? *flag : 1;
#pragma unroll
  for (int es = 0; es < 4; es++) {
#pragma unroll
    for (int rix = 0; rix < 4; rix++) {
      int rr = m0 + w*16 + quad*4 + rix;
      if (rr >= M) continue;
      int c = n0 + es*16 + l15;
      float val = acc[es][rix];
      if (epv == 4) {
        stout(OD, out_offv + ((size_t)z*1024 + rr)*64 + c, val, f);
      } else if (epv == 5) {
        O0[((size_t)z*64 + rr)*1024 + c] = val;
      } else if (epv == 6) {
        O0[((size_t)(32 + z)*64 + rr)*1024 + c] = val;
      }
    }
  }
}

// ---------------- attention forward: flash, MFMA bf16, software-pipelined ----------------
__global__ __launch_bounds__(256) void k_attn_fwd(
    const short* __restrict__ qb, const short* __restrict__ kb, const short* __restrict__ vbT,
    const float* __restrict__ gates,
    float* __restrict__ o, short* __restrict__ o_bf,
    float* __restrict__ mrow, float* __restrict__ lrow)
{
  int pp = blockIdx.x >> 8;
  int xx = (blockIdx.x >> 5) & 7;
  int bh = blockIdx.x & 31;
  int it = pp ? xx : (15 - xx);
  int i0 = it*64;
  int b = bh >> 3, h = bh & 7;
  __shared__ __align__(16) short Qs[64*QS];
  __shared__ __align__(16) short Ks[32*QS];
  __shared__ __align__(16) short VsT[64*TS];
  __shared__ __align__(16) short Ps[64*TS];
  int tid = threadIdx.x;
  int lane = tid & 63, w = tid >> 6;
  int l15 = lane & 15, quad = lane >> 4;
  int sr = tid >> 3, sc = (tid & 7) * 8;
  int sr2 = tid >> 2, sc2 = (tid & 3) * 8;
  int rsw = (l15 >> 2) & 3;
  for (int rr = sr; rr < 64; rr += 32)
    *(bf16x8*)&Qs[rr*QS + sc] = *(const bf16x8*)&qb[((size_t)bh*1024 + i0 + rr)*64 + sc];
  f32x4 oa[4] = {fz4(),fz4(),fz4(),fz4()};
  float m_st[4] = {-1e30f,-1e30f,-1e30f,-1e30f};
  float l_st[4] = {0.f,0.f,0.f,0.f};
  int jiters = 2*it + 2;
  bf16x8 rk = *(const bf16x8*)&kb[((size_t)bh*1024 + sr)*64 + sc];
  bf16x8 rv = *(const bf16x8*)&vbT[((size_t)bh*64 + sr2)*1024 + sc2];
  for (int jc = 0; jc < jiters; jc++) {
    int j0 = jc*32;
    __syncthreads();
    *(bf16x8*)&Ks[sr*QS + sc]    = rk;
    *(bf16x8*)&VsT[sr2*TS + sc2] = rv;
    __syncthreads();
    if (jc + 1 < jiters) {
      int j1 = j0 + 32;
      rk = *(const bf16x8*)&kb[((size_t)bh*1024 + j1 + sr)*64 + sc];
      rv = *(const bf16x8*)&vbT[((size_t)bh*64 + sr2)*1024 + j1 + sc2];
    }
    f32x4 sa[2] = {fz4(),fz4()};
#pragma unroll
    for (int kc = 0; kc < 64; kc += 32) {
      bf16x8 afr = *(const bf16x8*)&Qs[(w*16 + l15)*QS + kc + quad*8];
#pragma unroll
      for (int ni = 0; ni < 2; ni++) {
        bf16x8 bfr = *(const bf16x8*)&Ks[(ni*16 + l15)*QS + kc + quad*8];
        sa[ni] = MFMA16(afr, bfr, sa[ni]);
      }
    }
#pragma unroll
    for (int r = 0; r < 4; r++) {
      int gi = i0 + w*16 + quad*4 + r;
      float s0 = sa[0][r]*0.125f, s1 = sa[1][r]*0.125f;
      if (j0 + l15 > gi)      s0 = -1e30f;
      if (j0 + 16 + l15 > gi) s1 = -1e30f;
      float rm = fmaxf(s0, s1);
      rm = fmaxf(rm, __shfl_xor(rm, 1, 64));
      rm = fmaxf(rm, __shfl_xor(rm, 2, 64));
      rm = fmaxf(rm, __shfl_xor(rm, 4, 64));
      rm = fmaxf(rm, __shfl_xor(rm, 8, 64));
      float m_new = fmaxf(m_st[r], rm);
      float alpha = __expf(m_st[r] - m_new);
      float p0 = __expf(s0 - m_new), p1 = __expf(s1 - m_new);
      float rs = p0 + p1;
      rs += __shfl_xor(rs, 1, 64);
      rs += __shfl_xor(rs, 2, 64);
      rs += __shfl_xor(rs, 4, 64);
      rs += __shfl_xor(rs, 8, 64);
      l_st[r] = l_st[r]*alpha + rs;
      m_st[r] = m_new;
#pragma unroll
      for (int es = 0; es < 4; es++) oa[es][r] *= alpha;
      int rowp = w*16 + quad*4 + r;
      int lo3 = l15 & 7, g0 = l15 >> 3;
      Ps[rowp*TS + ((( g0      ^ quad) << 3) | lo3)] = f2bs(p0);
      Ps[rowp*TS + ((((g0 | 2) ^ quad) << 3) | lo3)] = f2bs(p1);
    }
    bf16x8 pa = *(const bf16x8*)&Ps[(w*16 + l15)*TS + ((quad ^ rsw) << 3)];
#pragma unroll
    for (int es = 0; es < 4; es++) {
      bf16x8 bv = *(const bf16x8*)&VsT[(es*16 + l15)*TS + quad*8];
      oa[es] = MFMA16(pa, bv, oa[es]);
    }
  }
#pragma unroll
  for (int r = 0; r < 4; r++) {
    int gi = i0 + w*16 + quad*4 + r;
    float g = gates[(size_t)bh*1024 + gi] / l_st[r];
#pragma unroll
    for (int es = 0; es < 4; es++) {
      float val = oa[es][r] * g;
      size_t oi = ((size_t)b*1024 + gi)*512 + h*64 + es*16 + l15;
      o[oi] = val;
      o_bf[oi] = f2bs(val);
    }
    if (l15 == 0) {
      mrow[(size_t)bh*1024 + gi] = m_st[r];
      lrow[(size_t)bh*1024 + gi] = l_st[r];
    }
  }
}

// ---------------- layernorm(tv) - pred -> err fp32 (in predf) + err_bf ----------------
__global__ void k_lnsub(const float* __restrict__ tvbuf, float* __restrict__ predf,
                        short* __restrict__ err_bf) {
  int r = blockIdx.x; int b = r / 1023; int prow = r + b;
  const float* tvr = tvbuf + (size_t)r*1024;
  __shared__ float red[256];
  float s1 = 0.f, s2 = 0.f;
  float xv[4];
#pragma unroll
  for (int i = 0; i < 4; i++) {
    xv[i] = tvr[threadIdx.x + 256*i];
    s1 += xv[i]; s2 += xv[i]*xv[i];
  }
  red[threadIdx.x] = s1; __syncthreads();
  for (int s = 128; s > 0; s >>= 1){ if (threadIdx.x < s) red[threadIdx.x] += red[threadIdx.x+s]; __syncthreads(); }
  float mean = red[0] / 1024.f; __syncthreads();
  red[threadIdx.x] = s2; __syncthreads();
  for (int s = 128; s > 0; s >>= 1){ if (threadIdx.x < s) red[threadIdx.x] += red[threadIdx.x+s]; __syncthreads(); }
  float var = red[0]/1024.f - mean*mean;
  float rstd = rsqrtf(var + 1e-5f);
  float* er = predf + (size_t)prow*1024;
#pragma unroll
  for (int i = 0; i < 4; i++) {
    int d = threadIdx.x + 256*i;
    float e = (xv[i]-mean)*rstd - er[d];
    er[d] = e;
    err_bf[(size_t)prow*1024 + d] = f2bs(e);
  }
}

// ---------------- k/du/q transposes + delta (fused, 1-D grid) ----------------
__global__ __launch_bounds__(256) void k_t16(const short* __restrict__ qv, const short* __restrict__ du,
                                             short* __restrict__ kbT, short* __restrict__ duT,
                                             short* __restrict__ qbT,
                                             const float* __restrict__ o, const float* __restrict__ gates,
                                             float* __restrict__ delta) {
  int bx = blockIdx.x; int tid = threadIdx.x;
  if (bx >= 1536) {
    int r = bx - 1536; int b = r / 1023; int n = r % 1023;
    int w = tid >> 6, lane = tid & 63;
    size_t base = ((size_t)b*1024 + n)*512;
    float p1 = bs2f(du[base + tid])       * o[base + tid];
    float p2 = bs2f(du[base + tid + 256]) * o[base + tid + 256];
    for (int s = 32; s > 0; s >>= 1) { p1 += __shfl_xor(p1, s, 64); p2 += __shfl_xor(p2, s, 64); }
    if (lane == 0) {
      size_t i1 = ((size_t)b*8 + w)*1024 + n;
      size_t i2 = ((size_t)b*8 + w + 4)*1024 + n;
      delta[i1] = p1 / gates[i1];
      delta[i2] = p2 / gates[i2];
    }
    return;
  }
  int z = bx >> 4;
  int r0 = (bx & 15)*64;
  const short* sb; short* db; int sld, nvalid;
  if (z < 32) {
    sb = qv + (size_t)(32 + z)*65536; sld = 64; nvalid = 1024;
    db = kbT + (size_t)z*65536;
  } else if (z < 64) {
    int zz = z - 32;
    sb = du + (size_t)(zz >> 3)*524288 + (size_t)(zz & 7)*64;
    sld = 512; nvalid = 1023;
    db = duT + (size_t)zz*65536;
  } else {
    int zz = z - 64;
    sb = qv + (size_t)zz*65536; sld = 64; nvalid = 1024;
    db = qbT + (size_t)zz*65536;
  }
  __shared__ float T[64][65];
  int sr = tid >> 3, sc = (tid & 7)*8;
  for (int rr = sr; rr < 64; rr += 32) {
    int n = r0 + rr;
    bf16x8 v = (n < nvalid) ? *(const bf16x8*)&sb[(size_t)n*sld + sc] : bz8();
#pragma unroll
    for (int j = 0; j < 8; j++) T[rr][sc+j] = bs2f(v[j]);
  }
  __syncthreads();
  int dc = tid >> 2, seg = tid & 3;
  bf16x8 o1, o2;
#pragma unroll
  for (int j = 0; j < 8; j++) { o1[j] = f2bs(T[seg*16+j][dc]); o2[j] = f2bs(T[seg*16+8+j][dc]); }
  *(bf16x8*)&db[(size_t)dc*1024 + r0 + seg*16]     = o1;
  *(bf16x8*)&db[(size_t)dc*1024 + r0 + seg*16 + 8] = o2;
}

// ---------------- attention backward, merged dv/dk (blocks 0..511) + dq (512..1023) ----------------
__global__ __launch_bounds__(256) void k_bwd(
    const short* __restrict__ qb, const short* __restrict__ kb, const short* __restrict__ vb,
    const short* __restrict__ du_bf, const short* __restrict__ qbT, const short* __restrict__ duT,
    const short* __restrict__ kbT,
    const float* __restrict__ mrow, const float* __restrict__ lrow, const float* __restrict__ delta,
    float* __restrict__ dv, float* __restrict__ dk, float* __restrict__ dq)
{
  __shared__ __align__(16) short smem[24320];
  int tid = threadIdx.x;
  int lane = tid & 63, w = tid >> 6;
  int l15 = lane & 15, quad = lane >> 4;
  int sr = tid >> 3, sc = (tid & 7) * 8;
  int sr2 = tid >> 2, sc2 = (tid & 3) * 8;
  int rsw = (l15 >> 2) & 3;

  if (blockIdx.x < 512) {
    int pp = blockIdx.x >> 8;
    int xx = (blockIdx.x >> 5) & 7;
    int bh = blockIdx.x & 31;
    int jt = pp ? (15 - xx) : xx;
    int j0 = jt*64;
    int b = bh >> 3, h = bh & 7;
    short* Ks   = smem;
    short* Vs   = Ks + 4608;
    short* Qs   = Vs + 4608;
    short* DUs  = Qs + 2304;
    short* QsT  = DUs + 2304;
    short* DUsT = QsT + 2560;
    short* PsT  = DUsT + 2560;
    short* DsT  = PsT + 2560;
    float* mvs  = (float*)(DsT + 2560);
    float* lvs  = mvs + 32;
    float* dls  = lvs + 32;
    for (int rr = sr; rr < 64; rr += 32) {
      *(bf16x8*)&Ks[rr*QS + sc] = *(const bf16x8*)&kb[((size_t)bh*1024 + j0 + rr)*64 + sc];
      *(bf16x8*)&Vs[rr*QS + sc] = *(const bf16x8*)&vb[((size_t)bh*1024 + j0 + rr)*64 + sc];
    }
    f32x4 dva[4] = {fz4(),fz4(),fz4(),fz4()};
    f32x4 dka[4] = {fz4(),fz4(),fz4(),fz4()};
    int iters = 32 - 2*jt;
    int gi0 = j0 + sr;
    bf16x8 rq   = *(const bf16x8*)&qb[((size_t)bh*1024 + gi0)*64 + sc];
    bf16x8 rdu  = (gi0 < NSR) ? *(const bf16x8*)&du_bf[((size_t)b*1024 + gi0)*512 + h*64 + sc] : bz8();
    bf16x8 rqT  = *(const bf16x8*)&qbT[((size_t)bh*64 + sr2)*1024 + j0 + sc2];
    bf16x8 rduT = *(const bf16x8*)&duT[((size_t)bh*64 + sr2)*1024 + j0 + sc2];
    float rm = 0.f, rl = 1.f, rd = 0.f;
    if (tid < 32) {
      int gi2 = j0 + tid;
      rm = mrow[(size_t)bh*1024 + gi2];
      rl = lrow[(size_t)bh*1024 + gi2];
      rd = (gi2 < NSR) ? delta[(size_t)bh*1024 + gi2] : 0.f;
    }
    for (int ic = 0; ic < iters; ic++) {
      int i0c = j0 + ic*32;
      __syncthreads();
      *(bf16x8*)&Qs[sr*QS + sc]    = rq;
      *(bf16x8*)&DUs[sr*QS + sc]   = rdu;
      *(bf16x8*)&QsT[sr2*TS + sc2]  = rqT;
      *(bf16x8*)&DUsT[sr2*TS + sc2] = rduT;
      if (tid < 32) { mvs[tid] = rm; lvs[tid] = 1.f/rl; dls[tid] = rd; }
      __syncthreads();
      if (ic + 1 < iters) {
        int i1 = i0c + 32;
        int g1 = i1 + sr;
        rq   = *(const bf16x8*)&qb[((size_t)bh*1024 + g1)*64 + sc];
        rdu  = (g1 < NSR) ? *(const bf16x8*)&du_bf[((size_t)b*1024 + g1)*512 + h*64 + sc] : bz8();
        rqT  = *(const bf16x8*)&qbT[((size_t)bh*64 + sr2)*1024 + i1 + sc2];
        rduT = *(const bf16x8*)&duT[((size_t)bh*64 + sr2)*1024 + i1 + sc2];
        if (tid < 32) {
          int gi2 = i1 + tid;
          rm = mrow[(size_t)bh*1024 + gi2];
          rl = lrow[(size_t)bh*1024 + gi2];
          rd = (gi2 < NSR) ? delta[(size_t)bh*1024 + gi2] : 0.f;
        }
      }
      f32x4 st[2] = {fz4(),fz4()};
      f32x4 dt[2] = {fz4(),fz4()};
#pragma unroll
      for (int kc = 0; kc < 64; kc += 32) {
        bf16x8 ak = *(const bf16x8*)&Ks[(w*16 + l15)*QS + kc + quad*8];
        bf16x8 av = *(const bf16x8*)&Vs[(w*16 + l15)*QS + kc + quad*8];
#pragma unroll
        for (int ni = 0; ni < 2; ni++) {
          bf16x8 bq = *(const bf16x8*)&Qs[(ni*16 + l15)*QS + kc + quad*8];
          bf16x8 bd = *(const bf16x8*)&DUs[(ni*16 + l15)*QS + kc + quad*8];
          st[ni] = MFMA16(ak, bq, st[ni]);
          dt[ni] = MFMA16(av, bd, dt[ni]);
        }
      }
#pragma unroll
      for (int ni = 0; ni < 2; ni++)
#pragma unroll
        for (int r = 0; r < 4; r++) {
          int gj = j0 + w*16 + quad*4 + r;
          int il = ni*16 + l15;
          int gi = i0c + il;
          float p = 0.f, dsc = 0.f;
          if (gi >= gj && gi < NSR && gj < NSR) {
            p = __expf(st[ni][r]*0.125f - mvs[il]) * lvs[il];
            dsc = 0.125f*p*(dt[ni][r] - dls[il]);
          }
          int rowp = w*16 + quad*4 + r;
          int pc = ((((ni << 1) | (l15 >> 3)) ^ quad) << 3) | (l15 & 7);
          PsT[rowp*TS + pc] = f2bs(p);
          DsT[rowp*TS + pc] = f2bs(dsc);
        }
      int rc = (quad ^ rsw) << 3;
      bf16x8 ap = *(const bf16x8*)&PsT[(w*16 + l15)*TS + rc];
      bf16x8 ad = *(const bf16x8*)&DsT[(w*16 + l15)*TS + rc];
#pragma unroll
      for (int es = 0; es < 4; es++) {
        bf16x8 bdu = *(const bf16x8*)&DUsT[(es*16 + l15)*TS + quad*8];
        bf16x8 bqt = *(const bf16x8*)&QsT[(es*16 + l15)*TS + quad*8];
        dva[es] = MFMA16(ap, bdu, dva[es]);
        dka[es] = MFMA16(ad, bqt, dka[es]);
      }
    }
#pragma unroll
    for (int r = 0; r < 4; r++) {
      int gj = j0 + w*16 + quad*4 + r;
#pragma unroll
      for (int es = 0; es < 4; es++) {
        dv[((size_t)bh*1024 + gj)*64 + es*16 + l15] = dva[es][r];
        dk[((size_t)bh*1024 + gj)*64 + es*16 + l15] = dka[es][r];
      }
    }
  } else {
    int bid = blockIdx.x - 512;
    int pp = bid >> 8;
    int xx = (bid >> 5) & 7;
    int bh = bid & 31;
    int it = pp ? xx : (15 - xx);
    int i0 = it*64;
    int b = bh >> 3, h = bh & 7;
    short* Qs  = smem;
    short* DUs = Qs + 4608;
    short* Ks  = DUs + 4608;
    short* Vs  = Ks + 2304;
    short* KsT = Vs + 2304;
    short* DsN = KsT + 2560;
    for (int rr = sr; rr < 64; rr += 32) {
      int gi = i0 + rr;
      *(bf16x8*)&Qs[rr*QS + sc] = *(const bf16x8*)&qb[((size_t)bh*1024 + gi)*64 + sc];
      bf16x8 duv = (gi < NSR) ? *(const bf16x8*)&du_bf[((size_t)b*1024 + gi)*512 + h*64 + sc] : bz8();
      *(bf16x8*)&DUs[rr*QS + sc] = duv;
    }
    float m4[4], li4[4], dl4[4];
#pragma unroll
    for (int r = 0; r < 4; r++) {
      int gi = i0 + w*16 + quad*4 + r;
      m4[r]  = mrow[(size_t)bh*1024 + gi];
      li4[r] = 1.f / lrow[(size_t)bh*1024 + gi];
      dl4[r] = (gi < NSR) ? delta[(size_t)bh*1024 + gi] : 0.f;
    }
    f32x4 dqa[4] = {fz4(),fz4(),fz4(),fz4()};
    int jiters = 2*it + 2;
    bf16x8 rk  = *(const bf16x8*)&kb[((size_t)bh*1024 + sr)*64 + sc];
    bf16x8 rv  = *(const bf16x8*)&vb[((size_t)bh*1024 + sr)*64 + sc];
    bf16x8 rkT = *(const bf16x8*)&kbT[((size_t)bh*64 + sr2)*1024 + sc2];
    for (int jc = 0; jc < jiters; jc++) {
      int j0 = jc*32;
      __syncthreads();
      *(bf16x8*)&Ks[sr*QS + sc]    = rk;
      *(bf16x8*)&Vs[sr*QS + sc]    = rv;
      *(bf16x8*)&KsT[sr2*TS + sc2] = rkT;
      __syncthreads();
      if (jc + 1 < jiters) {
        int j1 = j0 + 32;
        rk  = *(const bf16x8*)&kb[((size_t)bh*1024 + j1 + sr)*64 + sc];
        rv  = *(const bf16x8*)&vb[((size_t)bh*1024 + j1 + sr)*64 + sc];
        rkT = *(const bf16x8*)&kbT[((size_t)bh*64 + sr2)*1024 + j1 + sc2];
      }
      f32x4 st[2] = {fz4(),fz4()};
      f32x4 dt[2] = {fz4(),fz4()};
#pragma unroll
      for (int kc = 0; kc < 64; kc += 32) {
        bf16x8 aq = *(const bf16x8*)&Qs[(w*16 + l15)*QS + kc + quad*8];
        bf16x8 adu = *(const bf16x8*)&DUs[(w*16 + l15)*QS + kc + quad*8];
#pragma unroll
        for (int ni = 0; ni < 2; ni++) {
          bf16x8 bk = *(const bf16x8*)&Ks[(ni*16 + l15)*QS + kc + quad*8];
          bf16x8 bv = *(const bf16x8*)&Vs[(ni*16 + l15)*QS + kc + quad*8];
          st[ni] = MFMA16(aq, bk, st[ni]);
          dt[ni] = MFMA16(adu, bv, dt[ni]);
        }
      }
#pragma unroll
      for (int ni = 0; ni < 2; ni++)
#pragma unroll
        for (int r = 0; r < 4; r++) {
          int gi = i0 + w*16 + quad*4 + r;
          int gj = j0 + ni*16 + l15;
          float dsc = 0.f;
          if (gi >= gj && gi < NSR && gj < NSR) {
            float p = __expf(st[ni][r]*0.125f - m4[r]) * li4[r];
            dsc = 0.125f*p*(dt[ni][r] - dl4[r]);
          }
          int rowp = w*16 + quad*4 + r;
          int pc = ((((ni << 1) | (l15 >> 3)) ^ quad) << 3) | (l15 & 7);
          DsN[rowp*TS + pc] = f2bs(dsc);
        }
      bf16x8 ads = *(const bf16x8*)&DsN[(w*16 + l15)*TS + ((quad ^ rsw) << 3)];
#pragma unroll
      for (int es = 0; es < 4; es++) {
        bf16x8 bkt = *(const bf16x8*)&KsT[(es*16 + l15)*TS + quad*8];
        dqa[es] = MFMA16(ads, bkt, dqa[es]);
      }
    }
#pragma unroll
    for (int r = 0; r < 4; r++) {
      int gi = i0 + w*16 + quad*4 + r;
#pragma unroll
      for (int es = 0; es < 4; es++)
        dq[((size_t)bh*1024 + gi)*64 + es*16 + l15] = dqa[es][r];
    }
  }
}

// ---------------- NS phase 1: partial G = X X^T over K-slice + partial sumsq ----------------
__global__ __launch_bounds__(256) void k_ns_g(const float* __restrict__ Xsrc,
                                              float* __restrict__ Gpart, float* __restrict__ sspart) {
  int m = blockIdx.x, s = blockIdx.y;
  const float* Xm = Xsrc + (size_t)m*DH*DD;
  __shared__ __align__(16) short XGhi[64*GS], XGlo[64*GS];
  __shared__ float redz[4];
  int tid = threadIdx.x;
  int lane = tid & 63, w = tid >> 6;
  int l15 = lane & 15, quad = lane >> 4;
  int srow = tid >> 2, scol = (tid & 3)*8;
  int k0 = s*256;
  f32x4 accA[4] = {fz4(),fz4(),fz4(),fz4()};
  float ss = 0.f;
  float4 c1 = *(const float4*)&Xm[(size_t)srow*1024 + k0 + scol];
  float4 c2 = *(const float4*)&Xm[(size_t)srow*1024 + k0 + scol + 4];
  for (int kb = 0; kb < 256; kb += 32) {
    float xv[8] = {c1.x,c1.y,c1.z,c1.w,c2.x,c2.y,c2.z,c2.w};
    bf16x8 hi, lo;
#pragma unroll
    for (int j = 0; j < 8; j++) {
      short h = f2bs(xv[j]);
      hi[j] = h; lo[j] = f2bs(xv[j] - bs2f(h));
      ss += xv[j]*xv[j];
    }
    __syncthreads();
    *(bf16x8*)&XGhi[srow*GS + scol] = hi;
    *(bf16x8*)&XGlo[srow*GS + scol] = lo;
    __syncthreads();
    if (kb + 32 < 256) {
      c1 = *(const float4*)&Xm[(size_t)srow*1024 + k0 + kb + 32 + scol];
      c2 = *(const float4*)&Xm[(size_t)srow*1024 + k0 + kb + 32 + scol + 4];
    }
    bf16x8 ah = *(const bf16x8*)&XGhi[(w*16 + l15)*GS + quad*8];
    bf16x8 al = *(const bf16x8*)&XGlo[(w*16 + l15)*GS + quad*8];
#pragma unroll
    for (int es = 0; es < 4; es++) {
      bf16x8 bh = *(const bf16x8*)&XGhi[(es*16 + l15)*GS + quad*8];
      bf16x8 bl = *(const bf16x8*)&XGlo[(es*16 + l15)*GS + quad*8];
      accA[es] = MFMA16(ah, bh, accA[es]);
      accA[es] = MFMA16(ah, bl, accA[es]);
      accA[es] = MFMA16(al, bh, accA[es]);
    }
  }
  for (int st = 32; st > 0; st >>= 1) ss += __shfl_xor(ss, st, 64);
  if (lane == 0) redz[w] = ss;
  __syncthreads();
  if (tid == 0) sspart[m*4 + s] = redz[0]+redz[1]+redz[2]+redz[3];
  float* Gp = Gpart + (size_t)(m*4 + s)*4096;
#pragma unroll
  for (int es = 0; es < 4; es++)
#pragma unroll
    for (int rr = 0; rr < 4; rr++) {
      int row = w*16 + quad*4 + rr, col = es*16 + l15;
      Gp[row*64 + col] = accA[es][rr];
    }
}

// ---------------- NS phase 2: 5 iterations in 64x64 space -> M5, r ----------------
__global__ __launch_bounds__(256) void k_ns_iter(const float* __restrict__ Gpart, const float* __restrict__ sspart,
                                                 float* __restrict__ M5, float* __restrict__ rbuf) {
  int m = blockIdx.x;
  __shared__ __align__(16) short nsm[46080];
  short* Mhi  = nsm;
  short* Mlo  = nsm + 4608;
  short* MThi = nsm + 2*4608;
  short* MTlo = nsm + 3*4608;
  short* A0hi = nsm + 4*4608;
  short* A0lo = nsm + 5*4608;
  short* Shi  = nsm + 6*4608;
  short* Slo  = nsm + 7*4608;
  short* Aihi = nsm + 8*4608;
  short* Ailo = nsm + 9*4608;
  int tid = threadIdx.x;
  int lane = tid & 63, w = tid >> 6;
  int l15 = lane & 15, quad = lane >> 4;
  float tot = sspart[m*4] + sspart[m*4+1] + sspart[m*4+2] + sspart[m*4+3];
  float r_ = 1.f / (sqrtf(tot) + 1e-7f);
  float r2 = r_ * r_;
  const float* Gp = Gpart + (size_t)(m*4)*4096;
#pragma unroll
  for (int es = 0; es < 4; es++)
#pragma unroll
    for (int rr = 0; rr < 4; rr++) {
      int row = w*16 + quad*4 + rr, col = es*16 + l15;
      int idx = row*64 + col;
      float v = (Gp[idx] + Gp[4096 + idx] + Gp[8192 + idx] + Gp[12288 + idx]) * r2;
      short h = f2bs(v);
      A0hi[row*QS + col] = h;
      A0lo[row*QS + col] = f2bs(v - bs2f(h));
      short ih = (row == col) ? (short)0x3F80 : (short)0;
      Mhi[row*QS + col] = ih;  Mlo[row*QS + col] = 0;
      MThi[row*QS + col] = ih; MTlo[row*QS + col] = 0;
    }
  __syncthreads();
  for (int itn = 0; itn < 5; itn++) {
    f32x4 s4[4] = {fz4(),fz4(),fz4(),fz4()};
    mm64(Mhi, Mlo, A0hi, A0lo, s4, w, l15, quad);
    st_hl(Shi, Slo, s4, w, l15, quad);
    __syncthreads();
    f32x4 ai4[4] = {fz4(),fz4(),fz4(),fz4()};
    mm64(Shi, Slo, Mhi, Mlo, ai4, w, l15, quad);
    st_hl(Aihi, Ailo, ai4, w, l15, quad);
    __syncthreads();
    f32x4 a24[4] = {fz4(),fz4(),fz4(),fz4()};
    mm64(Aihi, Ailo, Aihi, Ailo, a24, w, l15, quad);
    f32x4 b4[4];
#pragma unroll
    for (int es = 0; es < 4; es++) b4[es] = NS_Bc*ai4[es] + NS_Cc*a24[es];
    st_hl(Shi, Slo, b4, w, l15, quad);
    __syncthreads();
    f32x4 m4[4] = {fz4(),fz4(),fz4(),fz4()};
    mm64(Shi, Slo, MThi, MTlo, m4, w, l15, quad);
#pragma unroll
    for (int es = 0; es < 4; es++)
#pragma unroll
      for (int rr = 0; rr < 4; rr++) {
        int row = w*16 + quad*4 + rr, col = es*16 + l15;
        float mold = bs2f(Mhi[row*QS + col]) + bs2f(Mlo[row*QS + col]);
        m4[es][rr] = NS_Ac*mold + m4[es][rr];
      }
    __syncthreads();
#pragma unroll
    for (int es = 0; es < 4; es++)
#pragma unroll
      for (int rr = 0; rr < 4; rr++) {
        int row = w*16 + quad*4 + rr, col = es*16 + l15;
        float x = m4[es][rr];
        short h = f2bs(x);
        short lo = f2bs(x - bs2f(h));
        Mhi[row*QS + col] = h;  Mlo[row*QS + col] = lo;
        MThi[col*QS + row] = h; MTlo[col*QS + row] = lo;
      }
    __syncthreads();
  }
#pragma unroll
  for (int es = 0; es < 4; es++)
#pragma unroll
    for (int rr = 0; rr < 4; rr++) {
      int row = w*16 + quad*4 + rr, col = es*16 + l15;
      M5[(size_t)m*4096 + row*64 + col] = bs2f(Mhi[row*QS + col]) + bs2f(Mlo[row*QS + col]);
    }
  if (tid == 0) rbuf[m] = r_;
}

// ---------------- NS phase 3: apply Y = r*(M5 X) + fused output ----------------
__global__ __launch_bounds__(256) void k_ns_apply(const float* __restrict__ Xsrc, const float* __restrict__ M5,
                                                  const float* __restrict__ rbuf, void* __restrict__ d_outv,
                                                  size_t off_dwv, size_t off_dwo, const int* __restrict__ flag) {
  int m = blockIdx.x, cs = blockIdx.y;
  const float* Xm = Xsrc + (size_t)m*DH*DD;
  const int f = *flag;
  float r_ = rbuf[m];
  __shared__ __align__(16) short Mhi[4608], Mlo[4608], XThi[4608], XTlo[4608];
  __shared__ float Sf[64*65];
  int tid = threadIdx.x;
  int lane = tid & 63, w = tid >> 6;
  int l15 = lane & 15, quad = lane >> 4;
  int srow = tid >> 2, scol = (tid & 3)*8;
  for (int i = tid; i < 4096; i += 256) {
    float v = M5[(size_t)m*4096 + i];
    int rowi = i >> 6, coli = i & 63;
    short h = f2bs(v);
    Mhi[rowi*QS + coli] = h;
    Mlo[rowi*QS + coli] = f2bs(v - bs2f(h));
  }
  int cbase = cs*256;
  float4 d1 = *(const float4*)&Xm[(size_t)srow*1024 + cbase + scol];
  float4 d2 = *(const float4*)&Xm[(size_t)srow*1024 + cbase + scol + 4];
  float4 d3 = *(const float4*)&Xm[(size_t)srow*1024 + cbase + scol + 32];
  float4 d4 = *(const float4*)&Xm[(size_t)srow*1024 + cbase + scol + 36];
  for (int cc = 0; cc < 256; cc += 64) {
    int c0 = cbase + cc;
    __syncthreads();
    {
      float xv0[8] = {d1.x,d1.y,d1.z,d1.w,d2.x,d2.y,d2.z,d2.w};
      float xv1[8] = {d3.x,d3.y,d3.z,d3.w,d4.x,d4.y,d4.z,d4.w};
#pragma unroll
      for (int j = 0; j < 8; j++) {
        int n0 = scol + j;
        short h0 = f2bs(xv0[j]);
        XThi[n0*QS + srow] = h0;
        XTlo[n0*QS + srow] = f2bs(xv0[j] - bs2f(h0));
        int n1 = scol + 32 + j;
        short h1 = f2bs(xv1[j]);
        XThi[n1*QS + srow] = h1;
        XTlo[n1*QS + srow] = f2bs(xv1[j] - bs2f(h1));
      }
    }
    __syncthreads();
    if (cc + 64 < 256) {
      d1 = *(const float4*)&Xm[(size_t)srow*1024 + c0 + 64 + scol];
      d2 = *(const float4*)&Xm[(size_t)srow*1024 + c0 + 64 + scol + 4];
      d3 = *(const float4*)&Xm[(size_t)srow*1024 + c0 + 64 + scol + 32];
      d4 = *(const float4*)&Xm[(size_t)srow*1024 + c0 + 64 + scol + 36];
    }
    f32x4 u4[4] = {fz4(),fz4(),fz4(),fz4()};
    mm64(Mhi, Mlo, XThi, XTlo, u4, w, l15, quad);
    if (m >= 32) {
#pragma unroll
      for (int es = 0; es < 4; es++)
#pragma unroll
        for (int rr = 0; rr < 4; rr++) {
          int row = w*16 + quad*4 + rr, col = c0 + es*16 + l15;
          stout(d_outv, off_dwo + (size_t)(m-32)*65536 + (size_t)row*1024 + col, r_*u4[es][rr], f);
        }
    } else {
#pragma unroll
      for (int es = 0; es < 4; es++)
#pragma unroll
        for (int rr = 0; rr < 4; rr++) {
          int row = w*16 + quad*4 + rr, col = es*16 + l15;
          Sf[col*65 + row] = r_*u4[es][rr];
        }
      __syncthreads();
      int dl = tid >> 2, e0 = (tid & 3)*16;
      size_t ob = off_dwv + (size_t)m*65536 + (size_t)(c0 + dl)*64 + e0;
#pragma unroll
      for (int j = 0; j < 16; j++)
        stout(d_outv, ob + j, Sf[dl*65 + e0 + j], f);
    }
  }
}

extern "C" void kernel_launch(void* const* d_in, const int* in_sizes, int n_in,
                              void* d_out, int out_size, void* d_ws, size_t ws_size,
                              hipStream_t stream) {
  const void* tokens   = d_in[0];
  const void* wq       = d_in[1];
  const void* wk       = d_in[2];
  const void* wv       = d_in[3];
  const void* wo       = d_in[4];
  const void* w_lr     = d_in[5];
  const void* w_target = d_in[6];
  const void* w_gates  = d_in[7];
  const void* rms_w    = d_in[8];

  const size_t off_dwq  = 4194304;
  const size_t off_dwk  = 6291456;
  const size_t off_dwv  = 8388608;
  const size_t off_dwo  = 10485760;

  float* ws = (float*)d_ws;
  float* t_    = ws;
  float* tvbuf = ws;
  short* errT  = (short*)ws;
  short* oT    = (short*)(ws + 2097152);
  short* t_bf  = (short*)(ws + 4194304);
  short* err_bf= (short*)(ws + 4194304);
  short* tT    = (short*)(ws + 6291456);
  short* qb    = (short*)(ws + 8388608);
  short* kbuf  = qb + 2097152;
  short* vbuf  = qb + 4194304;
  short* dqT   = (short*)(ws + 8388608);
  short* dkT   = dqT + 2097152;
  short* dvT   = dqT + 4194304;
  float* o_    = ws + 11534336;
  short* o_bf  = (short*)(ws + 13631488);
  short* du_bf = (short*)(ws + 13631488);
  float* predf = ws + 14680064;
  float* Xns   = ws + 14680064;
  short* BqkvT = (short*)(ws + 18874368);
  short* wtT   = (short*)(ws + 19660800);
  short* woT2  = (short*)(ws + 20185088);
  short* wo_bf = (short*)(ws + 20447232);
  float* gw    = ws + 20709376;
  float* lrw   = ws + 20717568;
  float* rms_f = ws + 20719616;
  float* dv_   = ws + 18874368;
  float* dk_   = ws + 20971520;
  float* dq_   = ws + 23068672;
  float* gates_= ws + 25165824;
  float* mrow_ = ws + 25198592;
  float* lrow_ = ws + 25231360;
  float* delta_= ws + 25264128;
  float* lr_   = ws + 25296896;
  float* mlr_  = ws + 25300992;
  int*   flag_ = (int*)(ws + 25305088);
  // transposed attention operands (time-multiplexed dead regions):
  short* vbT = (short*)(ws + 3145728);
  short* duT = (short*)(ws + 3145728);
  short* kbT = (short*)(ws + 4194304);
  short* qbT = (short*)ws;
  // NS scratch (dead regions): Gpart dv_/BqkvT area; M5b wtT area; rbuf/sspart woT2 area
  float* Gpart  = ws + 18874368;
  float* M5b    = ws + 19922944;
  float* rbuf   = ws + 20185088;
  float* sspart = ws + 20185152;

  hipLaunchKernelGGL(k_prep, dim3(1324), dim3(256), 0, stream, wq, wk, wv, w_target, wo, w_lr, w_gates, rms_w,
                     BqkvT, wtT, woT2, wo_bf, lrw, gw, rms_f, flag_);
  hipLaunchKernelGGL(k_rmsnorm, dim3(BB*NN), dim3(256), 0, stream, tokens, rms_f, gw, lrw,
                     t_, t_bf, gates_, lr_, mlr_, flag_);
  hipLaunchKernelGGL(k_transp, dim3(64,16,1), dim3(256), 0, stream, t_, (size_t)0, 1024, tT, (size_t)0, 4096, (const float*)nullptr, 0, 4096);

  hipLaunchKernelGGL(k_gemm2, dim3(32,12), dim3(256), 0, stream, t_bf, BqkvT, 1024, 1024, 1024, 4096, 0, 0,
                     (float*)nullptr, qb, (void*)nullptr, vbT, (const float*)nullptr, flag_,
                     0, (const short*)nullptr, (const short*)nullptr, 0, 0, 0, 0, 0, 0, (float*)nullptr, (void*)nullptr);
  hipLaunchKernelGGL(k_attn_fwd, dim3(512), dim3(256), 0, stream, qb, kbuf, vbT, gates_, o_, o_bf, mrow_, lrow_);
  // fused ep1 (y<8: pred) + ep2 (y>=8: tv)
  hipLaunchKernelGGL(k_gemm2, dim3(32,16), dim3(256), 0, stream, o_bf, woT2, 512, 512, 512, 4096, 0, 1,
                     predf, (short*)nullptr, d_out, (short*)nullptr, (const float*)nullptr, flag_,
                     8, t_bf, wtT, 1024, 1024, 1024, 4092, 1, 2, tvbuf, (void*)nullptr);
  hipLaunchKernelGGL(k_lnsub, dim3(BB*NSR), dim3(256), 0, stream, tvbuf, predf, err_bf);
  hipLaunchKernelGGL(k_gemm2, dim3(32,4), dim3(256), 0, stream, err_bf, wo_bf, 1024, 1024, 1024, 4092, 2, 3,
                     (float*)nullptr, du_bf, (void*)nullptr, (short*)nullptr, gates_, flag_,
                     0, (const short*)nullptr, (const short*)nullptr, 0, 0, 0, 0, 0, 0, (float*)nullptr, (void*)nullptr);
  hipLaunchKernelGGL(k_t16, dim3(1536 + BB*NSR), dim3(256), 0, stream, (const short*)qb, (const short*)du_bf,
                     kbT, duT, qbT, o_, gates_, delta_);
  hipLaunchKernelGGL(k_bwd, dim3(1024), dim3(256), 0, stream, qb, kbuf, vbuf, du_bf, qbT, duT, kbT,
                     mrow_, lrow_, delta_, dv_, dk_, dq_);
  hipLaunchKernelGGL(k_transp5, dim3(3072), dim3(256), 0, stream, dq_, dk_, dv_, predf, o_,
                     dqT, dkT, dvT, errT, oT, lr_, mlr_);
  hipLaunchKernelGGL(k_gemm_bf, dim3(16,1,64), dim3(256), 0, stream, tT, dqT, 4096, 1024, 1024, 1024, 0, 4,
                     (size_t)0,(size_t)1024,(size_t)65536,(size_t)0, (float*)nullptr, (short*)nullptr, d_out, off_dwq,
                     (const float*)nullptr, flag_, (const short*)nullptr, (const short*)dkT, (size_t)0, off_dwk, 1024);
  hipLaunchKernelGGL(k_gemm_bf, dim3(1,16,64), dim3(256), 0, stream, dvT, tT, 1024, 4096, 1024, 64, 0, 5,
                     (size_t)65536,(size_t)0,(size_t)0,(size_t)1024, Xns, (short*)nullptr, (void*)nullptr, (size_t)0,
                     (const float*)nullptr, flag_, (const short*)oT, (const short*)errT, (size_t)1048576, (size_t)0, 1024);
  hipLaunchKernelGGL(k_ns_g,     dim3(64,4), dim3(256), 0, stream, Xns, Gpart, sspart);
  hipLaunchKernelGGL(k_ns_iter,  dim3(64),   dim3(256), 0, stream, Gpart, sspart, M5b, rbuf);
  hipLaunchKernelGGL(k_ns_apply, dim3(64,4), dim3(256), 0, stream, Xns, M5b, rbuf, d_out, off_dwv, off_dwo, flag_);
  (void)in_sizes; (void)n_in; (void)out_size; (void)ws_size;
}

// Round 13
// 442.357 us; speedup vs baseline: 1.2439x; 1.0056x over previous
//
#include <hip/hip_runtime.h>
#include <hip/hip_bf16.h>
#include <math.h>

#define BB 4
#define NN 1024
#define DD 1024
#define HH 8
#define DH 64
#define NSR 1023

#define NS_Ac 3.4445f
#define NS_Bc (-4.775f)
#define NS_Cc 2.0315f

typedef short bf16x8 __attribute__((ext_vector_type(8)));
typedef float f32x4 __attribute__((ext_vector_type(4)));
#define MFMA16(a,b,c) __builtin_amdgcn_mfma_f32_16x16x32_bf16(a,b,c,0,0,0)

#define QS 72   // LDS row stride (bf16) for [rows][64] tiles
#define TS 40   // LDS row stride (bf16) for [rows][32] tiles
#define GS 40   // GEMM LDS row stride (bf16) for [64][32] tiles

static __device__ __forceinline__ float ldin(const void* p, size_t i, int f) {
  return f ? ((const float*)p)[i] : __bfloat162float(((const __hip_bfloat16*)p)[i]);
}
static __device__ __forceinline__ void stout(void* p, size_t i, float v, int f) {
  if (f) ((float*)p)[i] = v;
  else   ((__hip_bfloat16*)p)[i] = __float2bfloat16(v);
}
static __device__ __forceinline__ short f2bs(float x) {
  union { float f; unsigned u; } a; a.f = x;
  unsigned r = a.u + 0x7fffu + ((a.u >> 16) & 1u);
  return (short)(r >> 16);
}
static __device__ __forceinline__ float bs2f(short s) {
  union { unsigned u; float f; } a; a.u = ((unsigned)(unsigned short)s) << 16;
  return a.f;
}
static __device__ __forceinline__ f32x4 fz4() { f32x4 z = {0.f,0.f,0.f,0.f}; return z; }
static __device__ __forceinline__ bf16x8 bz8() { bf16x8 z = {0,0,0,0,0,0,0,0}; return z; }

// 64x64 split-bf16 matmul: C += A * B^T (A,B row-major [64][QS] hi/lo pairs in LDS)
static __device__ __forceinline__ void mm64(const short* __restrict__ Ah, const short* __restrict__ Al,
                                            const short* __restrict__ Bh, const short* __restrict__ Bl,
                                            f32x4* acc, int w, int l15, int quad) {
#pragma unroll
  for (int kc = 0; kc < 64; kc += 32) {
    bf16x8 ah = *(const bf16x8*)&Ah[(w*16 + l15)*QS + kc + quad*8];
    bf16x8 al = *(const bf16x8*)&Al[(w*16 + l15)*QS + kc + quad*8];
#pragma unroll
    for (int es = 0; es < 4; es++) {
      bf16x8 bh = *(const bf16x8*)&Bh[(es*16 + l15)*QS + kc + quad*8];
      bf16x8 bl = *(const bf16x8*)&Bl[(es*16 + l15)*QS + kc + quad*8];
      acc[es] = MFMA16(ah, bh, acc[es]);
      acc[es] = MFMA16(ah, bl, acc[es]);
      acc[es] = MFMA16(al, bh, acc[es]);
    }
  }
}
// write fragment (fp32) as hi/lo bf16 pair at output coords
static __device__ __forceinline__ void st_hl(short* __restrict__ Dh, short* __restrict__ Dl,
                                             const f32x4* v, int w, int l15, int quad) {
#pragma unroll
  for (int es = 0; es < 4; es++)
#pragma unroll
    for (int rr = 0; rr < 4; rr++) {
      int row = w*16 + quad*4 + rr, col = es*16 + l15;
      float x = v[es][rr];
      short h = f2bs(x);
      Dh[row*QS + col] = h;
      Dl[row*QS + col] = f2bs(x - bs2f(h));
    }
}

// ---------------- fused prep: all weight converters + small tensors + flag ----------------
__global__ __launch_bounds__(256) void k_prep(
    const void* wq, const void* wk, const void* wv,
    const void* w_target, const void* wo, const void* w_lr, const void* w_gates, const void* rms_w,
    short* __restrict__ BqkvT, short* __restrict__ wtT, short* __restrict__ woT2,
    short* __restrict__ wo_bf, float* __restrict__ lrw, float* __restrict__ gw,
    float* __restrict__ rms_f, int* __restrict__ flag)
{
  const int f = (((const unsigned short*)rms_w)[0] == 0x3F80) ? 0 : 1;
  int bx = blockIdx.x; int tid = threadIdx.x;
  if (bx >= 768) {
    if (bx < 812) {
      if (bx == 768 && tid == 0) *flag = f;
      int idx = (bx - 768)*256 + tid;
      if (idx < 2048) lrw[idx] = ldin(w_lr, idx, f);
      else if (idx < 10240) gw[idx-2048] = ldin(w_gates, idx-2048, f);
      else if (idx < 11264) rms_f[idx-10240] = ldin(rms_w, idx-10240, f);
    } else {
      size_t base = (size_t)(bx - 812)*1024;
#pragma unroll
      for (int j = 0; j < 4; j++) {
        size_t i2 = base + tid + 256*j;
        wo_bf[i2] = f2bs(ldin(wo, i2, f));
      }
    }
    return;
  }
  const void* src; short* dst; int sld, dld, srow0, scol0, drow0; size_t soff = 0;
  if (bx < 384) {
    int x = bx & 15, y = bx >> 4;
    int n0 = y*64; int which = n0 >> 9, h = (n0 >> 6) & 7;
    src = (which==0) ? wq : (which==1) ? wk : wv;
    soff = (size_t)h*65536;
    sld = 64; dld = 1024; srow0 = x*64; scol0 = 0; drow0 = n0; dst = BqkvT;
  } else if (bx < 640) {
    int r = bx - 384; int x = r & 15, y = r >> 4;
    src = w_target; dst = wtT; sld = 1024; dld = 1024;
    srow0 = x*64; scol0 = y*64; drow0 = scol0;
  } else {
    int r = bx - 640; int x = r & 7, y = r >> 3;
    src = wo; dst = woT2; sld = 1024; dld = 512;
    srow0 = x*64; scol0 = y*64; drow0 = scol0;
  }
  __shared__ float T[64][65];
  int r4 = tid >> 4, c4 = (tid & 15)*4;
  for (int rr = r4; rr < 64; rr += 16)
#pragma unroll
    for (int j = 0; j < 4; j++)
      T[rr][c4+j] = ldin(src, soff + (size_t)(srow0+rr)*sld + scol0 + c4 + j, f);
  __syncthreads();
  int dc = tid >> 2, seg = tid & 3;
  bf16x8 o1, o2;
#pragma unroll
  for (int j = 0; j < 8; j++) { o1[j] = f2bs(T[seg*16+j][dc]); o2[j] = f2bs(T[seg*16+8+j][dc]); }
  *(bf16x8*)&dst[(size_t)(drow0+dc)*dld + srow0 + seg*16]     = o1;
  *(bf16x8*)&dst[(size_t)(drow0+dc)*dld + srow0 + seg*16 + 8] = o2;
}

// ---------------- RMSNorm fused with gates + lr/mlr (reads converted gw/lrw/rms_f) ----------------
__global__ void k_rmsnorm(const void* __restrict__ tokens, const float* __restrict__ rms_f,
                          const float* __restrict__ gw, const float* __restrict__ lrw,
                          float* __restrict__ t, short* __restrict__ t_bf,
                          float* __restrict__ gates, float* __restrict__ lr, float* __restrict__ mlr,
                          const int* __restrict__ flag) {
  const int f = *flag;
  int row = blockIdx.x;
  int b = row >> 10, n = row & 1023;
  __shared__ float red[256];
  __shared__ float red2[4][10];
  float xv[4]; float acc = 0.f;
#pragma unroll
  for (int i = 0; i < 4; i++) {
    xv[i] = ldin(tokens, (size_t)row*DD + threadIdx.x + 256*i, f);
    acc += xv[i]*xv[i];
  }
  red[threadIdx.x] = acc; __syncthreads();
  for (int s = 128; s > 0; s >>= 1) { if (threadIdx.x < s) red[threadIdx.x] += red[threadIdx.x+s]; __syncthreads(); }
  float r = rsqrtf(red[0] / DD + 1.1920929e-07f);
  float a10[10] = {0,0,0,0,0,0,0,0,0,0};
#pragma unroll
  for (int i = 0; i < 4; i++) {
    int d = threadIdx.x + 256*i;
    float v = xv[i] * r * rms_f[d];
    t[(size_t)row*DD + d] = v;
    t_bf[(size_t)row*DD + d] = f2bs(v);
#pragma unroll
    for (int h = 0; h < HH; h++) a10[h] += v * gw[d*HH + h];
    a10[8] += v * lrw[d*2];
    a10[9] += v * lrw[d*2+1];
  }
  int lane = threadIdx.x & 63, w = threadIdx.x >> 6;
#pragma unroll
  for (int c = 0; c < 10; c++) {
    float a = a10[c];
    for (int s = 32; s > 0; s >>= 1) a += __shfl_xor(a, s, 64);
    if (lane == 0) red2[w][c] = a;
  }
  __syncthreads();
  if (threadIdx.x < 10) {
    int c = threadIdx.x;
    float sum = red2[0][c]+red2[1][c]+red2[2][c]+red2[3][c];
    float sg = 1.f / (1.f + __expf(-sum));
    if (c < 8)      gates[((size_t)b*HH + c)*NN + n] = sg;
    else if (c == 8) lr[row]  = sg * 0.01f;
    else             mlr[row] = sg * 0.01f;
  }
}

// fp32 [R][C] -> bf16 [C][R] (kept for the t->tT transpose)
__global__ __launch_bounds__(256) void k_transp(
    const float* __restrict__ src, size_t sStepZ, int sld,
    short* __restrict__ dst, size_t dStepZ, int dld,
    const float* __restrict__ coef, int zIsBh, int nz)
{
  int z = blockIdx.z;
  const float* sb = src + (size_t)z*sStepZ;
  short* db = dst + (size_t)z*dStepZ;
  const float* cb = coef ? coef + (size_t)(zIsBh ? (z>>3) : z)*1024 : (const float*)0;
  int x0 = blockIdx.x*64, y0 = blockIdx.y*64;
  __shared__ float T[64][65];
  int tid = threadIdx.x;
  int r4 = tid >> 4, c4 = (tid & 15)*4;
  for (int rr = r4; rr < 64; rr += 16) {
    int rg = x0 + rr;
    bool val = rg < nz;
    float cf = val ? (cb ? cb[rg] : 1.f) : 0.f;
    float4 v = val ? *(const float4*)&sb[(size_t)rg*sld + y0 + c4] : make_float4(0,0,0,0);
    T[rr][c4+0] = v.x*cf; T[rr][c4+1] = v.y*cf; T[rr][c4+2] = v.z*cf; T[rr][c4+3] = v.w*cf;
  }
  __syncthreads();
  int dc = tid >> 2, seg = tid & 3;
  bf16x8 o1, o2;
#pragma unroll
  for (int j = 0; j < 8; j++) { o1[j] = f2bs(T[seg*16+j][dc]); o2[j] = f2bs(T[seg*16+8+j][dc]); }
  *(bf16x8*)&db[(size_t)(y0+dc)*dld + x0 + seg*16]     = o1;
  *(bf16x8*)&db[(size_t)(y0+dc)*dld + x0 + seg*16 + 8] = o2;
}

// ---------------- 2-way fused fp32->bf16T transposes (errT + oT only; d* now done in k_bwd) ----------------
// [0,1024) predf->errT; [1024,1536) o->oT
__global__ __launch_bounds__(256) void k_transp5(
    const float* __restrict__ predf, const float* __restrict__ o,
    short* __restrict__ errT, short* __restrict__ oT,
    const float* __restrict__ mlr)
{
  int bx = blockIdx.x;
  const float* src; short* dst; const float* cb; int sld, dld, x0, y0;
  size_t sStep, dStep; int z;
  if (bx < 1024) {
    z = bx >> 8; x0 = (bx & 15)*64; y0 = ((bx >> 4) & 15)*64;
    src = predf; dst = errT; cb = (const float*)0;
    sld = 1024; dld = 1024; sStep = 1048576; dStep = 1048576;
  } else {
    int r = bx - 1024; z = r >> 7; x0 = (r & 15)*64; y0 = ((r >> 4) & 7)*64;
    src = o; dst = oT; cb = mlr + (size_t)z*1024;
    sld = 512; dld = 1024; sStep = 524288; dStep = 524288;
  }
  src += (size_t)z*sStep; dst += (size_t)z*dStep;
  __shared__ float T[64][65];
  int tid = threadIdx.x;
  int r4 = tid >> 4, c4 = (tid & 15)*4;
  for (int rr = r4; rr < 64; rr += 16) {
    int rg = x0 + rr;
    bool val = rg < 1023;
    float cf = val ? (cb ? cb[rg] : 1.f) : 0.f;
    float4 v = val ? *(const float4*)&src[(size_t)rg*sld + y0 + c4] : make_float4(0,0,0,0);
    T[rr][c4+0] = v.x*cf; T[rr][c4+1] = v.y*cf; T[rr][c4+2] = v.z*cf; T[rr][c4+3] = v.w*cf;
  }
  __syncthreads();
  int dc = tid >> 2, seg = tid & 3;
  bf16x8 o1, o2;
#pragma unroll
  for (int j = 0; j < 8; j++) { o1[j] = f2bs(T[seg*16+j][dc]); o2[j] = f2bs(T[seg*16+8+j][dc]); }
  *(bf16x8*)&dst[(size_t)(y0+dc)*dld + x0 + seg*16]     = o1;
  *(bf16x8*)&dst[(size_t)(y0+dc)*dld + x0 + seg*16 + 8] = o2;
}

// ---------------- 128x128 MFMA GEMM (big shapes): C[M x N] = A[M][K] * B^T ----------------
// Dual-mode: blocks with blockIdx.y >= ysplit use the second parameter set (fused launches).
__global__ __launch_bounds__(256) void k_gemm2(
    const short* __restrict__ A, const short* __restrict__ B,
    int lda, int ldb, int K, int M, int rowmode, int ep,
    float* __restrict__ O0, short* __restrict__ OS, void* __restrict__ OD,
    short* __restrict__ VT, const float* __restrict__ gates, const int* __restrict__ flag,
    int ysplit, const short* __restrict__ A2, const short* __restrict__ B2,
    int lda2, int ldb2, int K2, int M2, int rowmode2, int ep2p,
    float* __restrict__ O02, void* __restrict__ OD2)
{
  int yb = blockIdx.y;
  const short* Au = A; const short* Bu = B;
  int ldav = lda, ldbv = ldb, Kv = K, Mv = M, rmv = rowmode, epv = ep;
  float* O0v = O0; void* ODv = OD;
  if (ysplit && yb >= ysplit) {
    yb -= ysplit; Au = A2; Bu = B2; ldav = lda2; ldbv = ldb2; Kv = K2; Mv = M2;
    rmv = rowmode2; epv = ep2p; O0v = O02; ODv = OD2;
  }
  int m0 = blockIdx.x*128, n0 = yb*128;
  __shared__ __align__(16) short sm2[17408];
  short* As = sm2;          // 128*GS = 5120
  short* Bs = sm2 + 5120;   // 5120
  int tid = threadIdx.x;
  int lane = tid & 63, w = tid >> 6;
  int wr = w >> 1, wc = w & 1;
  int l15 = lane & 15, quad = lane >> 4;
  int row = tid >> 1, col16 = (tid & 1)*16;
  int r = m0 + row;
  int arow;
  if (rmv == 1)      { int b = r / 1023; arow = r + b + 1; }
  else if (rmv == 2) { int b = r / 1023; arow = r + b; }
  else arow = r;
  bool aval = (r < Mv);
  const short* Ap = Au + (size_t)arow*ldav + col16;
  const short* Bp = Bu + (size_t)(n0+row)*ldbv + col16;
  f32x4 acc[4][4];
#pragma unroll
  for (int mi = 0; mi < 4; mi++)
#pragma unroll
    for (int ni = 0; ni < 4; ni++) acc[mi][ni] = fz4();
  bf16x8 av0 = aval ? *(const bf16x8*)(Ap) : bz8();
  bf16x8 av1 = aval ? *(const bf16x8*)(Ap + 8) : bz8();
  bf16x8 bv0 = *(const bf16x8*)(Bp);
  bf16x8 bv1 = *(const bf16x8*)(Bp + 8);
  for (int kb = 0; kb < Kv; kb += 32) {
    __syncthreads();
    *(bf16x8*)&As[row*GS + col16]     = av0;
    *(bf16x8*)&As[row*GS + col16 + 8] = av1;
    *(bf16x8*)&Bs[row*GS + col16]     = bv0;
    *(bf16x8*)&Bs[row*GS + col16 + 8] = bv1;
    __syncthreads();
    if (kb + 32 < Kv) {
      av0 = aval ? *(const bf16x8*)(Ap + kb + 32) : bz8();
      av1 = aval ? *(const bf16x8*)(Ap + kb + 40) : bz8();
      bv0 = *(const bf16x8*)(Bp + kb + 32);
      bv1 = *(const bf16x8*)(Bp + kb + 40);
    }
    bf16x8 afr[4], bfr[4];
#pragma unroll
    for (int mi = 0; mi < 4; mi++)
      afr[mi] = *(const bf16x8*)&As[(wr*64 + mi*16 + l15)*GS + quad*8];
#pragma unroll
    for (int ni = 0; ni < 4; ni++)
      bfr[ni] = *(const bf16x8*)&Bs[(wc*64 + ni*16 + l15)*GS + quad*8];
#pragma unroll
    for (int mi = 0; mi < 4; mi++)
#pragma unroll
      for (int ni = 0; ni < 4; ni++)
        acc[mi][ni] = MFMA16(afr[mi], bfr[ni], acc[mi][ni]);
  }
  const int f = flag ? *flag : 1;
#pragma unroll
  for (int mi = 0; mi < 4; mi++)
#pragma unroll
    for (int ni = 0; ni < 4; ni++)
#pragma unroll
      for (int rix = 0; rix < 4; rix++) {
        int rr = m0 + wr*64 + mi*16 + quad*4 + rix;
        if (rr >= Mv) continue;
        int c = n0 + wc*64 + ni*16 + l15;
        float val = acc[mi][ni][rix];
        if (epv == 0) {
          int which = c >> 9; int h = (c >> 6) & 7; int e = c & 63;
          int b = rr >> 10; int n = rr & 1023;
          OS[(size_t)which*2097152 + (((size_t)b*8 + h)*1024 + n)*64 + e] = f2bs(val);
        } else if (epv == 1) {
          O0v[(size_t)rr*1024 + c] = val;
          stout(ODv, (size_t)rr*1024 + c, val, f);
        } else if (epv == 2) {
          O0v[(size_t)rr*1024 + c] = val;
        } else {
          int b = rr / 1023; int n = rr % 1023;
          int h = c >> 6;
          float g = gates[((size_t)b*8 + h)*1024 + n];
          OS[((size_t)b*1024 + n)*512 + c] = f2bs(val * g);
        }
      }
  // ep0: v-tiles (c in [1024,1536)) additionally write transposed vbT via LDS stage
  if (epv == 0 && n0 >= 1024) {
    short* ST = sm2;   // [128 c][136: m 0..63 at 0, m 64..127 at 72]
    __syncthreads();
#pragma unroll
    for (int mi = 0; mi < 4; mi++)
#pragma unroll
      for (int ni = 0; ni < 4; ni++)
#pragma unroll
        for (int rix = 0; rix < 4; rix++) {
          int ml = wr*64 + mi*16 + quad*4 + rix;
          int cl = wc*64 + ni*16 + l15;
          int mo = ml + ((ml >> 6) << 3);   // +8 if ml>=64
          ST[cl*136 + mo] = f2bs(acc[mi][ni][rix]);
        }
    __syncthreads();
    int r2 = tid >> 1;
    int sg = tid & 1;
    int cg = n0 + r2;
    int h = (cg >> 6) & 7;
    int e = cg & 63;
    int b = m0 >> 10;
    int bh = b*8 + h;
    size_t dst = ((size_t)bh*64 + e)*1024 + (m0 & 1023) + sg*64;
    int so = r2*136 + sg*72;
#pragma unroll
    for (int j = 0; j < 64; j += 8)
      *(bf16x8*)&VT[dst + j] = *(const bf16x8*)&ST[so + j];
  }
}

// ---------------- universal MFMA GEMM (64x64, K-step 64): kept for ep4/ep5 fused shapes ----------------
__global__ __launch_bounds__(256) void k_gemm_bf(
    const short* __restrict__ A, const short* __restrict__ B,
    int lda, int ldb, int K, int M, int rowmode, int ep,
    size_t aStepBh, size_t aStepB, size_t bStepBh, size_t bStepB,
    float* __restrict__ O0, short* __restrict__ OS, void* __restrict__ OD,
    size_t out_off, const float* __restrict__ gates, const int* __restrict__ flag,
    const short* __restrict__ A2, const short* __restrict__ B2,
    size_t bStepB2, size_t out_off2, int ldb2)
{
  int z = blockIdx.z;
  const short* Au = A; const short* Bu = B;
  size_t bStepBv = bStepB; size_t out_offv = out_off;
  int epv = ep; int ldbv = ldb;
  if (ep == 4 && z >= 32) { Bu = B2; out_offv = out_off2; z -= 32; }
  if (ep == 5 && z >= 32) { Au = A2; Bu = B2; bStepBv = bStepB2; ldbv = ldb2; epv = 6; z -= 32; }
  int zb = z >> 3;
  const short* Ab = Au + (size_t)z*aStepBh + (size_t)zb*aStepB;
  const short* Bb = Bu + (size_t)z*bStepBh + (size_t)zb*bStepBv;
  int m0 = blockIdx.x*64, n0 = blockIdx.y*64;
  __shared__ __align__(16) short AsBs[9216];
  short* As = AsBs;
  short* Bs = AsBs + 4608;
  int tid = threadIdx.x;
  int lane = tid & 63, w = tid >> 6;
  int l15 = lane & 15, quad = lane >> 4;
  int row = tid >> 2, col16 = (tid & 3)*16;
  int r = m0 + row;
  int arow;
  if (rowmode == 1)      { int b = r / 1023; arow = r + b + 1; }
  else if (rowmode == 2) { int b = r / 1023; arow = r + b; }
  else arow = r;
  bool aval = (r < M);
  const short* Ap = Ab + (size_t)arow*lda + col16;
  const short* Bp = Bb + (size_t)(n0+row)*ldbv + col16;
  f32x4 acc[4] = {fz4(),fz4(),fz4(),fz4()};
  bf16x8 av0 = aval ? *(const bf16x8*)(Ap) : bz8();
  bf16x8 av1 = aval ? *(const bf16x8*)(Ap + 8) : bz8();
  bf16x8 bv0 = *(const bf16x8*)(Bp);
  bf16x8 bv1 = *(const bf16x8*)(Bp + 8);
  for (int kb = 0; kb < K; kb += 64) {
    __syncthreads();
    *(bf16x8*)&As[row*QS + col16]     = av0;
    *(bf16x8*)&As[row*QS + col16 + 8] = av1;
    *(bf16x8*)&Bs[row*QS + col16]     = bv0;
    *(bf16x8*)&Bs[row*QS + col16 + 8] = bv1;
    __syncthreads();
    if (kb + 64 < K) {
      av0 = aval ? *(const bf16x8*)(Ap + kb + 64) : bz8();
      av1 = aval ? *(const bf16x8*)(Ap + kb + 72) : bz8();
      bv0 = *(const bf16x8*)(Bp + kb + 64);
      bv1 = *(const bf16x8*)(Bp + kb + 72);
    }
#pragma unroll
    for (int kc = 0; kc < 64; kc += 32) {
      bf16x8 afr = *(const bf16x8*)&As[(w*16 + l15)*QS + kc + quad*8];
#pragma unroll
      for (int es = 0; es < 4; es++) {
        bf16x8 bfr = *(const bf16x8*)&Bs[(es*16 + l15)*QS + kc + quad*8];
        acc[es] = MFMA16(afr, bfr, acc[es]);
      }
    }
  }
  const int f = flag ? *flag : 1;
#pragma unroll
  for (int es = 0; es < 4; es++) {
#pragma unroll
    for (int rix = 0; rix < 4; rix++) {
      int rr = m0 + w*16 + quad*4 + rix;
      if (rr >= M) continue;
      int c = n0 + es*16 + l15;
      float val = acc[es][rix];
      if (epv == 4) {
        stout(OD, out_offv + ((size_t)z*1024 + rr)*64 + c, val, f);
      } else if (epv == 5) {
        O0[((size_t)z*64 + rr)*1024 + c] = val;
      } else if (epv == 6) {
        O0[((size_t)(32 + z)*64 + rr)*1024 + c] = val;
      }
    }
  }
}

// ---------------- attention forward: flash, MFMA bf16, software-pipelined ----------------
__global__ __launch_bounds__(256) void k_attn_fwd(
    const short* __restrict__ qb, const short* __restrict__ kb, const short* __restrict__ vbT,
    const float* __restrict__ gates,
    float* __restrict__ o, short* __restrict__ o_bf,
    float* __restrict__ mrow, float* __restrict__ lrow)
{
  int pp = blockIdx.x >> 8;
  int xx = (blockIdx.x >> 5) & 7;
  int bh = blockIdx.x & 31;
  int it = pp ? xx : (15 - xx);
  int i0 = it*64;
  int b = bh >> 3, h = bh & 7;
  __shared__ __align__(16) short Qs[64*QS];
  __shared__ __align__(16) short Ks[32*QS];
  __shared__ __align__(16) short VsT[64*TS];
  __shared__ __align__(16) short Ps[64*TS];
  int tid = threadIdx.x;
  int lane = tid & 63, w = tid >> 6;
  int l15 = lane & 15, quad = lane >> 4;
  int sr = tid >> 3, sc = (tid & 7) * 8;
  int sr2 = tid >> 2, sc2 = (tid & 3) * 8;
  int rsw = (l15 >> 2) & 3;
  for (int rr = sr; rr < 64; rr += 32)
    *(bf16x8*)&Qs[rr*QS + sc] = *(const bf16x8*)&qb[((size_t)bh*1024 + i0 + rr)*64 + sc];
  f32x4 oa[4] = {fz4(),fz4(),fz4(),fz4()};
  float m_st[4] = {-1e30f,-1e30f,-1e30f,-1e30f};
  float l_st[4] = {0.f,0.f,0.f,0.f};
  int jiters = 2*it + 2;
  bf16x8 rk = *(const bf16x8*)&kb[((size_t)bh*1024 + sr)*64 + sc];
  bf16x8 rv = *(const bf16x8*)&vbT[((size_t)bh*64 + sr2)*1024 + sc2];
  for (int jc = 0; jc < jiters; jc++) {
    int j0 = jc*32;
    __syncthreads();
    *(bf16x8*)&Ks[sr*QS + sc]    = rk;
    *(bf16x8*)&VsT[sr2*TS + sc2] = rv;
    __syncthreads();
    if (jc + 1 < jiters) {
      int j1 = j0 + 32;
      rk = *(const bf16x8*)&kb[((size_t)bh*1024 + j1 + sr)*64 + sc];
      rv = *(const bf16x8*)&vbT[((size_t)bh*64 + sr2)*1024 + j1 + sc2];
    }
    f32x4 sa[2] = {fz4(),fz4()};
#pragma unroll
    for (int kc = 0; kc < 64; kc += 32) {
      bf16x8 afr = *(const bf16x8*)&Qs[(w*16 + l15)*QS + kc + quad*8];
#pragma unroll
      for (int ni = 0; ni < 2; ni++) {
        bf16x8 bfr = *(const bf16x8*)&Ks[(ni*16 + l15)*QS + kc + quad*8];
        sa[ni] = MFMA16(afr, bfr, sa[ni]);
      }
    }
#pragma unroll
    for (int r = 0; r < 4; r++) {
      int gi = i0 + w*16 + quad*4 + r;
      float s0 = sa[0][r]*0.125f, s1 = sa[1][r]*0.125f;
      if (j0 + l15 > gi)      s0 = -1e30f;
      if (j0 + 16 + l15 > gi) s1 = -1e30f;
      float rm = fmaxf(s0, s1);
      rm = fmaxf(rm, __shfl_xor(rm, 1, 64));
      rm = fmaxf(rm, __shfl_xor(rm, 2, 64));
      rm = fmaxf(rm, __shfl_xor(rm, 4, 64));
      rm = fmaxf(rm, __shfl_xor(rm, 8, 64));
      float m_new = fmaxf(m_st[r], rm);
      float alpha = __expf(m_st[r] - m_new);
      float p0 = __expf(s0 - m_new), p1 = __expf(s1 - m_new);
      float rs = p0 + p1;
      rs += __shfl_xor(rs, 1, 64);
      rs += __shfl_xor(rs, 2, 64);
      rs += __shfl_xor(rs, 4, 64);
      rs += __shfl_xor(rs, 8, 64);
      l_st[r] = l_st[r]*alpha + rs;
      m_st[r] = m_new;
#pragma unroll
      for (int es = 0; es < 4; es++) oa[es][r] *= alpha;
      int rowp = w*16 + quad*4 + r;
      int lo3 = l15 & 7, g0 = l15 >> 3;
      Ps[rowp*TS + ((( g0      ^ quad) << 3) | lo3)] = f2bs(p0);
      Ps[rowp*TS + ((((g0 | 2) ^ quad) << 3) | lo3)] = f2bs(p1);
    }
    bf16x8 pa = *(const bf16x8*)&Ps[(w*16 + l15)*TS + ((quad ^ rsw) << 3)];
#pragma unroll
    for (int es = 0; es < 4; es++) {
      bf16x8 bv = *(const bf16x8*)&VsT[(es*16 + l15)*TS + quad*8];
      oa[es] = MFMA16(pa, bv, oa[es]);
    }
  }
#pragma unroll
  for (int r = 0; r < 4; r++) {
    int gi = i0 + w*16 + quad*4 + r;
    float g = gates[(size_t)bh*1024 + gi] / l_st[r];
#pragma unroll
    for (int es = 0; es < 4; es++) {
      float val = oa[es][r] * g;
      size_t oi = ((size_t)b*1024 + gi)*512 + h*64 + es*16 + l15;
      o[oi] = val;
      o_bf[oi] = f2bs(val);
    }
    if (l15 == 0) {
      mrow[(size_t)bh*1024 + gi] = m_st[r];
      lrow[(size_t)bh*1024 + gi] = l_st[r];
    }
  }
}

// ---------------- layernorm(tv) - pred -> err fp32 (in predf) + err_bf ----------------
__global__ void k_lnsub(const float* __restrict__ tvbuf, float* __restrict__ predf,
                        short* __restrict__ err_bf) {
  int r = blockIdx.x; int b = r / 1023; int prow = r + b;
  const float* tvr = tvbuf + (size_t)r*1024;
  __shared__ float red[256];
  float s1 = 0.f, s2 = 0.f;
  float xv[4];
#pragma unroll
  for (int i = 0; i < 4; i++) {
    xv[i] = tvr[threadIdx.x + 256*i];
    s1 += xv[i]; s2 += xv[i]*xv[i];
  }
  red[threadIdx.x] = s1; __syncthreads();
  for (int s = 128; s > 0; s >>= 1){ if (threadIdx.x < s) red[threadIdx.x] += red[threadIdx.x+s]; __syncthreads(); }
  float mean = red[0] / 1024.f; __syncthreads();
  red[threadIdx.x] = s2; __syncthreads();
  for (int s = 128; s > 0; s >>= 1){ if (threadIdx.x < s) red[threadIdx.x] += red[threadIdx.x+s]; __syncthreads(); }
  float var = red[0]/1024.f - mean*mean;
  float rstd = rsqrtf(var + 1e-5f);
  float* er = predf + (size_t)prow*1024;
#pragma unroll
  for (int i = 0; i < 4; i++) {
    int d = threadIdx.x + 256*i;
    float e = (xv[i]-mean)*rstd - er[d];
    er[d] = e;
    err_bf[(size_t)prow*1024 + d] = f2bs(e);
  }
}

// ---------------- k/du/q transposes + delta (fused, 1-D grid) ----------------
__global__ __launch_bounds__(256) void k_t16(const short* __restrict__ qv, const short* __restrict__ du,
                                             short* __restrict__ kbT, short* __restrict__ duT,
                                             short* __restrict__ qbT,
                                             const float* __restrict__ o, const float* __restrict__ gates,
                                             float* __restrict__ delta) {
  int bx = blockIdx.x; int tid = threadIdx.x;
  if (bx >= 1536) {
    int r = bx - 1536; int b = r / 1023; int n = r % 1023;
    int w = tid >> 6, lane = tid & 63;
    size_t base = ((size_t)b*1024 + n)*512;
    float p1 = bs2f(du[base + tid])       * o[base + tid];
    float p2 = bs2f(du[base + tid + 256]) * o[base + tid + 256];
    for (int s = 32; s > 0; s >>= 1) { p1 += __shfl_xor(p1, s, 64); p2 += __shfl_xor(p2, s, 64); }
    if (lane == 0) {
      size_t i1 = ((size_t)b*8 + w)*1024 + n;
      size_t i2 = ((size_t)b*8 + w + 4)*1024 + n;
      delta[i1] = p1 / gates[i1];
      delta[i2] = p2 / gates[i2];
    }
    return;
  }
  int z = bx >> 4;
  int r0 = (bx & 15)*64;
  const short* sb; short* db; int sld, nvalid;
  if (z < 32) {
    sb = qv + (size_t)(32 + z)*65536; sld = 64; nvalid = 1024;
    db = kbT + (size_t)z*65536;
  } else if (z < 64) {
    int zz = z - 32;
    sb = du + (size_t)(zz >> 3)*524288 + (size_t)(zz & 7)*64;
    sld = 512; nvalid = 1023;
    db = duT + (size_t)zz*65536;
  } else {
    int zz = z - 64;
    sb = qv + (size_t)zz*65536; sld = 64; nvalid = 1024;
    db = qbT + (size_t)zz*65536;
  }
  __shared__ float T[64][65];
  int sr = tid >> 3, sc = (tid & 7)*8;
  for (int rr = sr; rr < 64; rr += 32) {
    int n = r0 + rr;
    bf16x8 v = (n < nvalid) ? *(const bf16x8*)&sb[(size_t)n*sld + sc] : bz8();
#pragma unroll
    for (int j = 0; j < 8; j++) T[rr][sc+j] = bs2f(v[j]);
  }
  __syncthreads();
  int dc = tid >> 2, seg = tid & 3;
  bf16x8 o1, o2;
#pragma unroll
  for (int j = 0; j < 8; j++) { o1[j] = f2bs(T[seg*16+j][dc]); o2[j] = f2bs(T[seg*16+8+j][dc]); }
  *(bf16x8*)&db[(size_t)dc*1024 + r0 + seg*16]     = o1;
  *(bf16x8*)&db[(size_t)dc*1024 + r0 + seg*16 + 8] = o2;
}

// ---------------- attention backward, merged dv/dk (blocks 0..511) + dq (512..1023) ----------------
// NEW: epilogues write scaled+transposed bf16 directly to dvT/dkT/dqT via LDS stage.
__global__ __launch_bounds__(256) void k_bwd(
    const short* __restrict__ qb, const short* __restrict__ kb, const short* __restrict__ vb,
    const short* __restrict__ du_bf, const short* __restrict__ qbT, const short* __restrict__ duT,
    const short* __restrict__ kbT,
    const float* __restrict__ mrow, const float* __restrict__ lrow, const float* __restrict__ delta,
    short* __restrict__ dvT, short* __restrict__ dkT, short* __restrict__ dqT,
    const float* __restrict__ lr, const float* __restrict__ mlr)
{
  __shared__ __align__(16) short smem[24320];
  int tid = threadIdx.x;
  int lane = tid & 63, w = tid >> 6;
  int l15 = lane & 15, quad = lane >> 4;
  int sr = tid >> 3, sc = (tid & 7) * 8;
  int sr2 = tid >> 2, sc2 = (tid & 3) * 8;
  int rsw = (l15 >> 2) & 3;

  if (blockIdx.x < 512) {
    int pp = blockIdx.x >> 8;
    int xx = (blockIdx.x >> 5) & 7;
    int bh = blockIdx.x & 31;
    int jt = pp ? (15 - xx) : xx;
    int j0 = jt*64;
    int b = bh >> 3, h = bh & 7;
    short* Ks   = smem;
    short* Vs   = Ks + 4608;
    short* Qs   = Vs + 4608;
    short* DUs  = Qs + 2304;
    short* QsT  = DUs + 2304;
    short* DUsT = QsT + 2560;
    short* PsT  = DUsT + 2560;
    short* DsT  = PsT + 2560;
    float* mvs  = (float*)(DsT + 2560);
    float* lvs  = mvs + 32;
    float* dls  = lvs + 32;
    for (int rr = sr; rr < 64; rr += 32) {
      *(bf16x8*)&Ks[rr*QS + sc] = *(const bf16x8*)&kb[((size_t)bh*1024 + j0 + rr)*64 + sc];
      *(bf16x8*)&Vs[rr*QS + sc] = *(const bf16x8*)&vb[((size_t)bh*1024 + j0 + rr)*64 + sc];
    }
    f32x4 dva[4] = {fz4(),fz4(),fz4(),fz4()};
    f32x4 dka[4] = {fz4(),fz4(),fz4(),fz4()};
    int iters = 32 - 2*jt;
    int gi0 = j0 + sr;
    bf16x8 rq   = *(const bf16x8*)&qb[((size_t)bh*1024 + gi0)*64 + sc];
    bf16x8 rdu  = (gi0 < NSR) ? *(const bf16x8*)&du_bf[((size_t)b*1024 + gi0)*512 + h*64 + sc] : bz8();
    bf16x8 rqT  = *(const bf16x8*)&qbT[((size_t)bh*64 + sr2)*1024 + j0 + sc2];
    bf16x8 rduT = *(const bf16x8*)&duT[((size_t)bh*64 + sr2)*1024 + j0 + sc2];
    float rm = 0.f, rl = 1.f, rd = 0.f;
    if (tid < 32) {
      int gi2 = j0 + tid;
      rm = mrow[(size_t)bh*1024 + gi2];
      rl = lrow[(size_t)bh*1024 + gi2];
      rd = (gi2 < NSR) ? delta[(size_t)bh*1024 + gi2] : 0.f;
    }
    for (int ic = 0; ic < iters; ic++) {
      int i0c = j0 + ic*32;
      __syncthreads();
      *(bf16x8*)&Qs[sr*QS + sc]    = rq;
      *(bf16x8*)&DUs[sr*QS + sc]   = rdu;
      *(bf16x8*)&QsT[sr2*TS + sc2]  = rqT;
      *(bf16x8*)&DUsT[sr2*TS + sc2] = rduT;
      if (tid < 32) { mvs[tid] = rm; lvs[tid] = 1.f/rl; dls[tid] = rd; }
      __syncthreads();
      if (ic + 1 < iters) {
        int i1 = i0c + 32;
        int g1 = i1 + sr;
        rq   = *(const bf16x8*)&qb[((size_t)bh*1024 + g1)*64 + sc];
        rdu  = (g1 < NSR) ? *(const bf16x8*)&du_bf[((size_t)b*1024 + g1)*512 + h*64 + sc] : bz8();
        rqT  = *(const bf16x8*)&qbT[((size_t)bh*64 + sr2)*1024 + i1 + sc2];
        rduT = *(const bf16x8*)&duT[((size_t)bh*64 + sr2)*1024 + i1 + sc2];
        if (tid < 32) {
          int gi2 = i1 + tid;
          rm = mrow[(size_t)bh*1024 + gi2];
          rl = lrow[(size_t)bh*1024 + gi2];
          rd = (gi2 < NSR) ? delta[(size_t)bh*1024 + gi2] : 0.f;
        }
      }
      f32x4 st[2] = {fz4(),fz4()};
      f32x4 dt[2] = {fz4(),fz4()};
#pragma unroll
      for (int kc = 0; kc < 64; kc += 32) {
        bf16x8 ak = *(const bf16x8*)&Ks[(w*16 + l15)*QS + kc + quad*8];
        bf16x8 av = *(const bf16x8*)&Vs[(w*16 + l15)*QS + kc + quad*8];
#pragma unroll
        for (int ni = 0; ni < 2; ni++) {
          bf16x8 bq = *(const bf16x8*)&Qs[(ni*16 + l15)*QS + kc + quad*8];
          bf16x8 bd = *(const bf16x8*)&DUs[(ni*16 + l15)*QS + kc + quad*8];
          st[ni] = MFMA16(ak, bq, st[ni]);
          dt[ni] = MFMA16(av, bd, dt[ni]);
        }
      }
#pragma unroll
      for (int ni = 0; ni < 2; ni++)
#pragma unroll
        for (int r = 0; r < 4; r++) {
          int gj = j0 + w*16 + quad*4 + r;
          int il = ni*16 + l15;
          int gi = i0c + il;
          float p = 0.f, dsc = 0.f;
          if (gi >= gj && gi < NSR && gj < NSR) {
            p = __expf(st[ni][r]*0.125f - mvs[il]) * lvs[il];
            dsc = 0.125f*p*(dt[ni][r] - dls[il]);
          }
          int rowp = w*16 + quad*4 + r;
          int pc = ((((ni << 1) | (l15 >> 3)) ^ quad) << 3) | (l15 & 7);
          PsT[rowp*TS + pc] = f2bs(p);
          DsT[rowp*TS + pc] = f2bs(dsc);
        }
      int rc = (quad ^ rsw) << 3;
      bf16x8 ap = *(const bf16x8*)&PsT[(w*16 + l15)*TS + rc];
      bf16x8 ad = *(const bf16x8*)&DsT[(w*16 + l15)*TS + rc];
#pragma unroll
      for (int es = 0; es < 4; es++) {
        bf16x8 bdu = *(const bf16x8*)&DUsT[(es*16 + l15)*TS + quad*8];
        bf16x8 bqt = *(const bf16x8*)&QsT[(es*16 + l15)*TS + quad*8];
        dva[es] = MFMA16(ap, bdu, dva[es]);
        dka[es] = MFMA16(ad, bqt, dka[es]);
      }
    }
    // epilogue: scale + transpose to dvT/dkT (bf16) via LDS stage
    __syncthreads();
    short* T1 = smem;          // dv tile [64 e][QS]
    short* T2 = smem + 4608;   // dk tile
#pragma unroll
    for (int r = 0; r < 4; r++) {
      int gj = j0 + w*16 + quad*4 + r;
      float cl = (gj < NSR) ? lr[(size_t)b*1024 + gj] : 0.f;
      float cm = (gj < NSR) ? mlr[(size_t)b*1024 + gj] : 0.f;
      int rl2 = w*16 + quad*4 + r;
#pragma unroll
      for (int es = 0; es < 4; es++) {
        T1[(es*16 + l15)*QS + rl2] = f2bs(dva[es][r]*cm);
        T2[(es*16 + l15)*QS + rl2] = f2bs(dka[es][r]*cl);
      }
    }
    __syncthreads();
    int e = tid >> 2, seg = (tid & 3)*16;
    size_t ob = (size_t)bh*65536 + (size_t)e*1024 + j0 + seg;
    *(bf16x8*)&dvT[ob]     = *(const bf16x8*)&T1[e*QS + seg];
    *(bf16x8*)&dvT[ob + 8] = *(const bf16x8*)&T1[e*QS + seg + 8];
    *(bf16x8*)&dkT[ob]     = *(const bf16x8*)&T2[e*QS + seg];
    *(bf16x8*)&dkT[ob + 8] = *(const bf16x8*)&T2[e*QS + seg + 8];
  } else {
    int bid = blockIdx.x - 512;
    int pp = bid >> 8;
    int xx = (bid >> 5) & 7;
    int bh = bid & 31;
    int it = pp ? xx : (15 - xx);
    int i0 = it*64;
    int b = bh >> 3, h = bh & 7;
    short* Qs  = smem;
    short* DUs = Qs + 4608;
    short* Ks  = DUs + 4608;
    short* Vs  = Ks + 2304;
    short* KsT = Vs + 2304;
    short* DsN = KsT + 2560;
    for (int rr = sr; rr < 64; rr += 32) {
      int gi = i0 + rr;
      *(bf16x8*)&Qs[rr*QS + sc] = *(const bf16x8*)&qb[((size_t)bh*1024 + gi)*64 + sc];
      bf16x8 duv = (gi < NSR) ? *(const bf16x8*)&du_bf[((size_t)b*1024 + gi)*512 + h*64 + sc] : bz8();
      *(bf16x8*)&DUs[rr*QS + sc] = duv;
    }
    float m4[4], li4[4], dl4[4];
#pragma unroll
    for (int r = 0; r < 4; r++) {
      int gi = i0 + w*16 + quad*4 + r;
      m4[r]  = mrow[(size_t)bh*1024 + gi];
      li4[r] = 1.f / lrow[(size_t)bh*1024 + gi];
      dl4[r] = (gi < NSR) ? delta[(size_t)bh*1024 + gi] : 0.f;
    }
    f32x4 dqa[4] = {fz4(),fz4(),fz4(),fz4()};
    int jiters = 2*it + 2;
    bf16x8 rk  = *(const bf16x8*)&kb[((size_t)bh*1024 + sr)*64 + sc];
    bf16x8 rv  = *(const bf16x8*)&vb[((size_t)bh*1024 + sr)*64 + sc];
    bf16x8 rkT = *(const bf16x8*)&kbT[((size_t)bh*64 + sr2)*1024 + sc2];
    for (int jc = 0; jc < jiters; jc++) {
      int j0 = jc*32;
      __syncthreads();
      *(bf16x8*)&Ks[sr*QS + sc]    = rk;
      *(bf16x8*)&Vs[sr*QS + sc]    = rv;
      *(bf16x8*)&KsT[sr2*TS + sc2] = rkT;
      __syncthreads();
      if (jc + 1 < jiters) {
        int j1 = j0 + 32;
        rk  = *(const bf16x8*)&kb[((size_t)bh*1024 + j1 + sr)*64 + sc];
        rv  = *(const bf16x8*)&vb[((size_t)bh*1024 + j1 + sr)*64 + sc];
        rkT = *(const bf16x8*)&kbT[((size_t)bh*64 + sr2)*1024 + j1 + sc2];
      }
      f32x4 st[2] = {fz4(),fz4()};
      f32x4 dt[2] = {fz4(),fz4()};
#pragma unroll
      for (int kc = 0; kc < 64; kc += 32) {
        bf16x8 aq = *(const bf16x8*)&Qs[(w*16 + l15)*QS + kc + quad*8];
        bf16x8 adu = *(const bf16x8*)&DUs[(w*16 + l15)*QS + kc + quad*8];
#pragma unroll
        for (int ni = 0; ni < 2; ni++) {
          bf16x8 bk = *(const bf16x8*)&Ks[(ni*16 + l15)*QS + kc + quad*8];
          bf16x8 bv = *(const bf16x8*)&Vs[(ni*16 + l15)*QS + kc + quad*8];
          st[ni] = MFMA16(aq, bk, st[ni]);
          dt[ni] = MFMA16(adu, bv, dt[ni]);
        }
      }
#pragma unroll
      for (int ni = 0; ni < 2; ni++)
#pragma unroll
        for (int r = 0; r < 4; r++) {
          int gi = i0 + w*16 + quad*4 + r;
          int gj = j0 + ni*16 + l15;
          float dsc = 0.f;
          if (gi >= gj && gi < NSR && gj < NSR) {
            float p = __expf(st[ni][r]*0.125f - m4[r]) * li4[r];
            dsc = 0.125f*p*(dt[ni][r] - dl4[r]);
          }
          int rowp = w*16 + quad*4 + r;
          int pc = ((((ni << 1) | (l15 >> 3)) ^ quad) << 3) | (l15 & 7);
          DsN[rowp*TS + pc] = f2bs(dsc);
        }
      bf16x8 ads = *(const bf16x8*)&DsN[(w*16 + l15)*TS + ((quad ^ rsw) << 3)];
#pragma unroll
      for (int es = 0; es < 4; es++) {
        bf16x8 bkt = *(const bf16x8*)&KsT[(es*16 + l15)*TS + quad*8];
        dqa[es] = MFMA16(ads, bkt, dqa[es]);
      }
    }
    // epilogue: scale + transpose to dqT (bf16) via LDS stage
    __syncthreads();
    short* T1 = smem;
#pragma unroll
    for (int r = 0; r < 4; r++) {
      int gi = i0 + w*16 + quad*4 + r;
      float cl = (gi < NSR) ? lr[(size_t)b*1024 + gi] : 0.f;
      int rl2 = w*16 + quad*4 + r;
#pragma unroll
      for (int es = 0; es < 4; es++)
        T1[(es*16 + l15)*QS + rl2] = f2bs(dqa[es][r]*cl);
    }
    __syncthreads();
    int e = tid >> 2, seg = (tid & 3)*16;
    size_t ob = (size_t)bh*65536 + (size_t)e*1024 + i0 + seg;
    *(bf16x8*)&dqT[ob]     = *(const bf16x8*)&T1[e*QS + seg];
    *(bf16x8*)&dqT[ob + 8] = *(const bf16x8*)&T1[e*QS + seg + 8];
  }
}

// ---------------- NS phase 1: partial G = X X^T over K-slice + partial sumsq ----------------
__global__ __launch_bounds__(256) void k_ns_g(const float* __restrict__ Xsrc,
                                              float* __restrict__ Gpart, float* __restrict__ sspart) {
  int m = blockIdx.x, s = blockIdx.y;
  const float* Xm = Xsrc + (size_t)m*DH*DD;
  __shared__ __align__(16) short XGhi[64*GS], XGlo[64*GS];
  __shared__ float redz[4];
  int tid = threadIdx.x;
  int lane = tid & 63, w = tid >> 6;
  int l15 = lane & 15, quad = lane >> 4;
  int srow = tid >> 2, scol = (tid & 3)*8;
  int k0 = s*256;
  f32x4 accA[4] = {fz4(),fz4(),fz4(),fz4()};
  float ss = 0.f;
  float4 c1 = *(const float4*)&Xm[(size_t)srow*1024 + k0 + scol];
  float4 c2 = *(const float4*)&Xm[(size_t)srow*1024 + k0 + scol + 4];
  for (int kb = 0; kb < 256; kb += 32) {
    float xv[8] = {c1.x,c1.y,c1.z,c1.w,c2.x,c2.y,c2.z,c2.w};
    bf16x8 hi, lo;
#pragma unroll
    for (int j = 0; j < 8; j++) {
      short h = f2bs(xv[j]);
      hi[j] = h; lo[j] = f2bs(xv[j] - bs2f(h));
      ss += xv[j]*xv[j];
    }
    __syncthreads();
    *(bf16x8*)&XGhi[srow*GS + scol] = hi;
    *(bf16x8*)&XGlo[srow*GS + scol] = lo;
    __syncthreads();
    if (kb + 32 < 256) {
      c1 = *(const float4*)&Xm[(size_t)srow*1024 + k0 + kb + 32 + scol];
      c2 = *(const float4*)&Xm[(size_t)srow*1024 + k0 + kb + 32 + scol + 4];
    }
    bf16x8 ah = *(const bf16x8*)&XGhi[(w*16 + l15)*GS + quad*8];
    bf16x8 al = *(const bf16x8*)&XGlo[(w*16 + l15)*GS + quad*8];
#pragma unroll
    for (int es = 0; es < 4; es++) {
      bf16x8 bh = *(const bf16x8*)&XGhi[(es*16 + l15)*GS + quad*8];
      bf16x8 bl = *(const bf16x8*)&XGlo[(es*16 + l15)*GS + quad*8];
      accA[es] = MFMA16(ah, bh, accA[es]);
      accA[es] = MFMA16(ah, bl, accA[es]);
      accA[es] = MFMA16(al, bh, accA[es]);
    }
  }
  for (int st = 32; st > 0; st >>= 1) ss += __shfl_xor(ss, st, 64);
  if (lane == 0) redz[w] = ss;
  __syncthreads();
  if (tid == 0) sspart[m*4 + s] = redz[0]+redz[1]+redz[2]+redz[3];
  float* Gp = Gpart + (size_t)(m*4 + s)*4096;
#pragma unroll
  for (int es = 0; es < 4; es++)
#pragma unroll
    for (int rr = 0; rr < 4; rr++) {
      int row = w*16 + quad*4 + rr, col = es*16 + l15;
      Gp[row*64 + col] = accA[es][rr];
    }
}

// ---------------- NS phase 2: 5 iterations in 64x64 space -> M5, r ----------------
__global__ __launch_bounds__(256) void k_ns_iter(const float* __restrict__ Gpart, const float* __restrict__ sspart,
                                                 float* __restrict__ M5, float* __restrict__ rbuf) {
  int m = blockIdx.x;
  __shared__ __align__(16) short nsm[46080];
  short* Mhi  = nsm;
  short* Mlo  = nsm + 4608;
  short* MThi = nsm + 2*4608;
  short* MTlo = nsm + 3*4608;
  short* A0hi = nsm + 4*4608;
  short* A0lo = nsm + 5*4608;
  short* Shi  = nsm + 6*4608;
  short* Slo  = nsm + 7*4608;
  short* Aihi = nsm + 8*4608;
  short* Ailo = nsm + 9*4608;
  int tid = threadIdx.x;
  int lane = tid & 63, w = tid >> 6;
  int l15 = lane & 15, quad = lane >> 4;
  float tot = sspart[m*4] + sspart[m*4+1] + sspart[m*4+2] + sspart[m*4+3];
  float r_ = 1.f / (sqrtf(tot) + 1e-7f);
  float r2 = r_ * r_;
  const float* Gp = Gpart + (size_t)(m*4)*4096;
#pragma unroll
  for (int es = 0; es < 4; es++)
#pragma unroll
    for (int rr = 0; rr < 4; rr++) {
      int row = w*16 + quad*4 + rr, col = es*16 + l15;
      int idx = row*64 + col;
      float v = (Gp[idx] + Gp[4096 + idx] + Gp[8192 + idx] + Gp[12288 + idx]) * r2;
      short h = f2bs(v);
      A0hi[row*QS + col] = h;
      A0lo[row*QS + col] = f2bs(v - bs2f(h));
      short ih = (row == col) ? (short)0x3F80 : (short)0;
      Mhi[row*QS + col] = ih;  Mlo[row*QS + col] = 0;
      MThi[row*QS + col] = ih; MTlo[row*QS + col] = 0;
    }
  __syncthreads();
  for (int itn = 0; itn < 5; itn++) {
    f32x4 s4[4] = {fz4(),fz4(),fz4(),fz4()};
    mm64(Mhi, Mlo, A0hi, A0lo, s4, w, l15, quad);
    st_hl(Shi, Slo, s4, w, l15, quad);
    __syncthreads();
    f32x4 ai4[4] = {fz4(),fz4(),fz4(),fz4()};
    mm64(Shi, Slo, Mhi, Mlo, ai4, w, l15, quad);
    st_hl(Aihi, Ailo, ai4, w, l15, quad);
    __syncthreads();
    f32x4 a24[4] = {fz4(),fz4(),fz4(),fz4()};
    mm64(Aihi, Ailo, Aihi, Ailo, a24, w, l15, quad);
    f32x4 b4[4];
#pragma unroll
    for (int es = 0; es < 4; es++) b4[es] = NS_Bc*ai4[es] + NS_Cc*a24[es];
    st_hl(Shi, Slo, b4, w, l15, quad);
    __syncthreads();
    f32x4 m4[4] = {fz4(),fz4(),fz4(),fz4()};
    mm64(Shi, Slo, MThi, MTlo, m4, w, l15, quad);
#pragma unroll
    for (int es = 0; es < 4; es++)
#pragma unroll
      for (int rr = 0; rr < 4; rr++) {
        int row = w*16 + quad*4 + rr, col = es*16 + l15;
        float mold = bs2f(Mhi[row*QS + col]) + bs2f(Mlo[row*QS + col]);
        m4[es][rr] = NS_Ac*mold + m4[es][rr];
      }
    __syncthreads();
#pragma unroll
    for (int es = 0; es < 4; es++)
#pragma unroll
      for (int rr = 0; rr < 4; rr++) {
        int row = w*16 + quad*4 + rr, col = es*16 + l15;
        float x = m4[es][rr];
        short h = f2bs(x);
        short lo = f2bs(x - bs2f(h));
        Mhi[row*QS + col] = h;  Mlo[row*QS + col] = lo;
        MThi[col*QS + row] = h; MTlo[col*QS + row] = lo;
      }
    __syncthreads();
  }
#pragma unroll
  for (int es = 0; es < 4; es++)
#pragma unroll
    for (int rr = 0; rr < 4; rr++) {
      int row = w*16 + quad*4 + rr, col = es*16 + l15;
      M5[(size_t)m*4096 + row*64 + col] = bs2f(Mhi[row*QS + col]) + bs2f(Mlo[row*QS + col]);
    }
  if (tid == 0) rbuf[m] = r_;
}

// ---------------- NS phase 3: apply Y = r*(M5 X) + fused output ----------------
__global__ __launch_bounds__(256) void k_ns_apply(const float* __restrict__ Xsrc, const float* __restrict__ M5,
                                                  const float* __restrict__ rbuf, void* __restrict__ d_outv,
                                                  size_t off_dwv, size_t off_dwo, const int* __restrict__ flag) {
  int m = blockIdx.x, cs = blockIdx.y;
  const float* Xm = Xsrc + (size_t)m*DH*DD;
  const int f = *flag;
  float r_ = rbuf[m];
  __shared__ __align__(16) short Mhi[4608], Mlo[4608], XThi[4608], XTlo[4608];
  __shared__ float Sf[64*65];
  int tid = threadIdx.x;
  int lane = tid & 63, w = tid >> 6;
  int l15 = lane & 15, quad = lane >> 4;
  int srow = tid >> 2, scol = (tid & 3)*8;
  for (int i = tid; i < 4096; i += 256) {
    float v = M5[(size_t)m*4096 + i];
    int rowi = i >> 6, coli = i & 63;
    short h = f2bs(v);
    Mhi[rowi*QS + coli] = h;
    Mlo[rowi*QS + coli] = f2bs(v - bs2f(h));
  }
  int cbase = cs*256;
  float4 d1 = *(const float4*)&Xm[(size_t)srow*1024 + cbase + scol];
  float4 d2 = *(const float4*)&Xm[(size_t)srow*1024 + cbase + scol + 4];
  float4 d3 = *(const float4*)&Xm[(size_t)srow*1024 + cbase + scol + 32];
  float4 d4 = *(const float4*)&Xm[(size_t)srow*1024 + cbase + scol + 36];
  for (int cc = 0; cc < 256; cc += 64) {
    int c0 = cbase + cc;
    __syncthreads();
    {
      float xv0[8] = {d1.x,d1.y,d1.z,d1.w,d2.x,d2.y,d2.z,d2.w};
      float xv1[8] = {d3.x,d3.y,d3.z,d3.w,d4.x,d4.y,d4.z,d4.w};
#pragma unroll
      for (int j = 0; j < 8; j++) {
        int n0 = scol + j;
        short h0 = f2bs(xv0[j]);
        XThi[n0*QS + srow] = h0;
        XTlo[n0*QS + srow] = f2bs(xv0[j] - bs2f(h0));
        int n1 = scol + 32 + j;
        short h1 = f2bs(xv1[j]);
        XThi[n1*QS + srow] = h1;
        XTlo[n1*QS + srow] = f2bs(xv1[j] - bs2f(h1));
      }
    }
    __syncthreads();
    if (cc + 64 < 256) {
      d1 = *(const float4*)&Xm[(size_t)srow*1024 + c0 + 64 + scol];
      d2 = *(const float4*)&Xm[(size_t)srow*1024 + c0 + 64 + scol + 4];
      d3 = *(const float4*)&Xm[(size_t)srow*1024 + c0 + 64 + scol + 32];
      d4 = *(const float4*)&Xm[(size_t)srow*1024 + c0 + 64 + scol + 36];
    }
    f32x4 u4[4] = {fz4(),fz4(),fz4(),fz4()};
    mm64(Mhi, Mlo, XThi, XTlo, u4, w, l15, quad);
    if (m >= 32) {
#pragma unroll
      for (int es = 0; es < 4; es++)
#pragma unroll
        for (int rr = 0; rr < 4; rr++) {
          int row = w*16 + quad*4 + rr, col = c0 + es*16 + l15;
          stout(d_outv, off_dwo + (size_t)(m-32)*65536 + (size_t)row*1024 + col, r_*u4[es][rr], f);
        }
    } else {
#pragma unroll
      for (int es = 0; es < 4; es++)
#pragma unroll
        for (int rr = 0; rr < 4; rr++) {
          int row = w*16 + quad*4 + rr, col = es*16 + l15;
          Sf[col*65 + row] = r_*u4[es][rr];
        }
      __syncthreads();
      int dl = tid >> 2, e0 = (tid & 3)*16;
      size_t ob = off_dwv + (size_t)m*65536 + (size_t)(c0 + dl)*64 + e0;
#pragma unroll
      for (int j = 0; j < 16; j++)
        stout(d_outv, ob + j, Sf[dl*65 + e0 + j], f);
    }
  }
}

extern "C" void kernel_launch(void* const* d_in, const int* in_sizes, int n_in,
                              void* d_out, int out_size, void* d_ws, size_t ws_size,
                              hipStream_t stream) {
  const void* tokens   = d_in[0];
  const void* wq       = d_in[1];
  const void* wk       = d_in[2];
  const void* wv       = d_in[3];
  const void* wo       = d_in[4];
  const void* w_lr     = d_in[5];
  const void* w_target = d_in[6];
  const void* w_gates  = d_in[7];
  const void* rms_w    = d_in[8];

  const size_t off_dwq  = 4194304;
  const size_t off_dwk  = 6291456;
  const size_t off_dwv  = 8388608;
  const size_t off_dwo  = 10485760;

  float* ws = (float*)d_ws;
  float* t_    = ws;
  float* tvbuf = ws;
  short* errT  = (short*)ws;
  short* oT    = (short*)(ws + 2097152);
  short* t_bf  = (short*)(ws + 4194304);
  short* err_bf= (short*)(ws + 4194304);
  short* tT    = (short*)(ws + 6291456);
  short* qb    = (short*)(ws + 8388608);
  short* kbuf  = qb + 2097152;
  short* vbuf  = qb + 4194304;
  float* o_    = ws + 11534336;
  short* o_bf  = (short*)(ws + 13631488);
  short* du_bf = (short*)(ws + 13631488);
  float* predf = ws + 14680064;
  float* Xns   = ws + 14680064;
  short* BqkvT = (short*)(ws + 18874368);
  short* wtT   = (short*)(ws + 19660800);
  short* woT2  = (short*)(ws + 20185088);
  short* wo_bf = (short*)(ws + 20447232);
  float* gw    = ws + 20709376;
  float* lrw   = ws + 20717568;
  float* rms_f = ws + 20719616;
  float* gates_= ws + 25165824;
  float* mrow_ = ws + 25198592;
  float* lrow_ = ws + 25231360;
  float* delta_= ws + 25264128;
  float* lr_   = ws + 25296896;
  float* mlr_  = ws + 25300992;
  int*   flag_ = (int*)(ws + 25305088);
  // transposed attention operands (time-multiplexed dead regions):
  short* vbT = (short*)(ws + 3145728);
  short* duT = (short*)(ws + 3145728);
  short* kbT = (short*)(ws + 4194304);
  short* qbT = (short*)ws;
  // d* transposed outputs written DIRECTLY by k_bwd (must not alias qb/kbuf/vbuf which k_bwd reads):
  // dqT [18874368,19922944) floats (old dv_ region; BqkvT/wtT dead by then)
  // dkT [20971520,22020096) floats (old dk_ region)
  // dvT [23068672,24117248) floats (old dq_ region)
  short* dqT = (short*)(ws + 18874368);
  short* dkT = (short*)(ws + 20971520);
  short* dvT = (short*)(ws + 23068672);
  // NS scratch: Gpart overlaps dqT region (written after ep4 consumed dqT); M5b/rbuf/sspart in dead weight regions
  float* Gpart  = ws + 18874368;
  float* M5b    = ws + 19922944;
  float* rbuf   = ws + 20185088;
  float* sspart = ws + 20185152;

  hipLaunchKernelGGL(k_prep, dim3(1324), dim3(256), 0, stream, wq, wk, wv, w_target, wo, w_lr, w_gates, rms_w,
                     BqkvT, wtT, woT2, wo_bf, lrw, gw, rms_f, flag_);
  hipLaunchKernelGGL(k_rmsnorm, dim3(BB*NN), dim3(256), 0, stream, tokens, rms_f, gw, lrw,
                     t_, t_bf, gates_, lr_, mlr_, flag_);
  hipLaunchKernelGGL(k_transp, dim3(64,16,1), dim3(256), 0, stream, t_, (size_t)0, 1024, tT, (size_t)0, 4096, (const float*)nullptr, 0, 4096);

  hipLaunchKernelGGL(k_gemm2, dim3(32,12), dim3(256), 0, stream, t_bf, BqkvT, 1024, 1024, 1024, 4096, 0, 0,
                     (float*)nullptr, qb, (void*)nullptr, vbT, (const float*)nullptr, flag_,
                     0, (const short*)nullptr, (const short*)nullptr, 0, 0, 0, 0, 0, 0, (float*)nullptr, (void*)nullptr);
  hipLaunchKernelGGL(k_attn_fwd, dim3(512), dim3(256), 0, stream, qb, kbuf, vbT, gates_, o_, o_bf, mrow_, lrow_);
  // fused ep1 (y<8: pred) + ep2 (y>=8: tv)
  hipLaunchKernelGGL(k_gemm2, dim3(32,16), dim3(256), 0, stream, o_bf, woT2, 512, 512, 512, 4096, 0, 1,
                     predf, (short*)nullptr, d_out, (short*)nullptr, (const float*)nullptr, flag_,
                     8, t_bf, wtT, 1024, 1024, 1024, 4092, 1, 2, tvbuf, (void*)nullptr);
  hipLaunchKernelGGL(k_lnsub, dim3(BB*NSR), dim3(256), 0, stream, tvbuf, predf, err_bf);
  hipLaunchKernelGGL(k_gemm2, dim3(32,4), dim3(256), 0, stream, err_bf, wo_bf, 1024, 1024, 1024, 4092, 2, 3,
                     (float*)nullptr, du_bf, (void*)nullptr, (short*)nullptr, gates_, flag_,
                     0, (const short*)nullptr, (const short*)nullptr, 0, 0, 0, 0, 0, 0, (float*)nullptr, (void*)nullptr);
  hipLaunchKernelGGL(k_t16, dim3(1536 + BB*NSR), dim3(256), 0, stream, (const short*)qb, (const short*)du_bf,
                     kbT, duT, qbT, o_, gates_, delta_);
  hipLaunchKernelGGL(k_bwd, dim3(1024), dim3(256), 0, stream, qb, kbuf, vbuf, du_bf, qbT, duT, kbT,
                     mrow_, lrow_, delta_, dvT, dkT, dqT, lr_, mlr_);
  hipLaunchKernelGGL(k_transp5, dim3(1536), dim3(256), 0, stream, predf, o_, errT, oT, mlr_);
  hipLaunchKernelGGL(k_gemm_bf, dim3(16,1,64), dim3(256), 0, stream, tT, dqT, 4096, 1024, 1024, 1024, 0, 4,
                     (size_t)0,(size_t)1024,(size_t)65536,(size_t)0, (float*)nullptr, (short*)nullptr, d_out, off_dwq,
                     (const float*)nullptr, flag_, (const short*)nullptr, (const short*)dkT, (size_t)0, off_dwk, 1024);
  hipLaunchKernelGGL(k_gemm_bf, dim3(1,16,64), dim3(256), 0, stream, dvT, tT, 1024, 4096, 1024, 64, 0, 5,
                     (size_t)65536,(size_t)0,(size_t)0,(size_t)1024, Xns, (short*)nullptr, (void*)nullptr, (size_t)0,
                     (const float*)nullptr, flag_, (const short*)oT, (const short*)errT, (size_t)1048576, (size_t)0, 1024);
  hipLaunchKernelGGL(k_ns_g,     dim3(64,4), dim3(256), 0, stream, Xns, Gpart, sspart);
  hipLaunchKernelGGL(k_ns_iter,  dim3(64),   dim3(256), 0, stream, Gpart, sspart, M5b, rbuf);
  hipLaunchKernelGGL(k_ns_apply, dim3(64,4), dim3(256), 0, stream, Xns, M5b, rbuf, d_out, off_dwv, off_dwo, flag_);
  (void)in_sizes; (void)n_in; (void)out_size; (void)ws_size;
}